// Round 2
// baseline (1419.678 us; speedup 1.0000x reference)
//
#include <hip/hip_runtime.h>
#include <math.h>

// ---------------------------------------------------------------------------
// AttentionRoutingDetector — R7: ASRC=1 mgemm path drops LDS staging entirely.
// Rationale: each wave owns its 32 A-rows exclusively (no cross-wave sharing),
// and pre-split A planes are row-major = exact fragment byte order, so each
// lane's MFMA A-fragment is a contiguous 16B global segment. Removing the
// global->reg->LDS->reg round trip deletes both per-kt barriers, the vmcnt(0)
// +lgkmcnt(0) barrier drains, and all LDS bank conflicts. W fragments were
// already direct-from-global (coalesced 1KB/wave). MFMA sequence per
// accumulator unchanged -> bit-identical numerics. ASRC=0/2 keep LDS path.
// XCD swizzle (R6) retained.
// ---------------------------------------------------------------------------

#define B_ALL 32

typedef __attribute__((ext_vector_type(8))) short short8;
typedef __attribute__((ext_vector_type(4))) float f32x4;

__device__ __forceinline__ unsigned short f2bf(float x) {
    unsigned u = __float_as_uint(x);
    return (unsigned short)((u + 0x7FFFu + ((u >> 16) & 1u)) >> 16);
}
__device__ __forceinline__ float bf2f(unsigned short h) {
    return __uint_as_float(((unsigned)h) << 16);
}
__device__ __forceinline__ unsigned pk(unsigned short a, unsigned short b) {
    return (unsigned)a | ((unsigned)b << 16);
}

// ---------------- conv1: (b,3,512,512) -> relu -> (b,64,256,256), stride 2
__global__ __launch_bounds__(256) void conv1_kernel(
    const float* __restrict__ img, const float* __restrict__ w,
    const float* __restrict__ bias, float* __restrict__ x1, int b0)
{
    const int ow = threadIdx.x;
    const int oh = blockIdx.x;
    const int bl = blockIdx.y;
    const int b  = b0 + bl;

    const float* ib = img + (size_t)b * 3 * 512 * 512;
    float in[3][3][3];
#pragma unroll
    for (int c = 0; c < 3; c++)
#pragma unroll
        for (int kh = 0; kh < 3; kh++) {
            int ih = oh * 2 + kh;
#pragma unroll
            for (int kw = 0; kw < 3; kw++) {
                int iw = ow * 2 + kw;
                in[c][kh][kw] = (ih < 512 && iw < 512)
                    ? ib[((size_t)c * 512 + ih) * 512 + iw] : 0.f;
            }
        }

    float* ob = x1 + ((size_t)bl * 64 * 256 + oh) * 256 + ow;
#pragma unroll 2
    for (int oc = 0; oc < 64; oc++) {
        const float* wp = w + oc * 27;
        float p[3] = {0.f, 0.f, 0.f};
#pragma unroll
        for (int c = 0; c < 3; c++)
#pragma unroll
            for (int kh = 0; kh < 3; kh++)
#pragma unroll
                for (int kw = 0; kw < 3; kw++)
                    p[c] = fmaf(in[c][kh][kw], wp[(c * 3 + kh) * 3 + kw], p[c]);
        double s = (double)bias[oc] + ((double)p[0] + (double)p[1] + (double)p[2]);
        float r = (float)s;
        ob[(size_t)oc * 256 * 256] = r > 0.f ? r : 0.f;
    }
}

// ---------------- conv2 weight transpose: w[oc][ic][kh][kw] -> wt[ic][kh][kw][oc]
__global__ __launch_bounds__(256) void wprep_conv2(
    const float* __restrict__ w, float* __restrict__ wt)
{
    int idx = blockIdx.x * 256 + threadIdx.x;
    if (idx >= 64 * 9 * 64) return;
    int oc = idx & 63;
    int r  = idx >> 6;          // ic*9 + kh*3 + kw
    wt[r * 64 + oc] = w[(size_t)oc * 576 + r];
}

// ---------------- conv2 + fused 8x8 pool partials (no LDS, no barriers).
__global__ __launch_bounds__(256, 3) void conv2_kernel(
    const float* __restrict__ x1, const float* __restrict__ wt,
    const float* __restrict__ bias, double* __restrict__ tokd)
{
    const int tid  = threadIdx.x;
    const int lane = tid & 63;
    const int wave = __builtin_amdgcn_readfirstlane(tid >> 6);   // 0..3, scalar
    const int oh   = blockIdx.x;          // 0..127
    const int bl   = blockIdx.y;
    const int ow0  = lane * 2;            // this thread: ow0, ow0+1

    const float* xb = x1 + (size_t)bl * 64 * 256 * 256;

    float  acc[2][16];
    double accd[2][16];
#pragma unroll
    for (int j = 0; j < 2; j++)
#pragma unroll
        for (int o = 0; o < 16; o++) { acc[j][o] = 0.f; accd[j][o] = 0.0; }

    for (int ic0 = 0; ic0 < 64; ic0 += 8) {
#pragma unroll 2
        for (int ic = 0; ic < 8; ic++) {
            const int icg = ic0 + ic;
#pragma unroll
            for (int kh = 0; kh < 3; kh++) {
                const int ih = oh * 2 + kh;
                if (ih < 256) {
                    const float* rp = xb + ((size_t)icg * 256 + ih) * 256 + ow0 * 2;
                    float4 f4 = *(const float4*)rp;            // cols 4L..4L+3
                    float  f5 = (ow0 < 126) ? rp[4] : 0.f;     // col 4L+4 (lane63 OOB=0)
                    float iv[3][2] = {{f4.x, f4.z}, {f4.y, f4.w}, {f4.z, f5}};
                    const float* wrow = wt + (size_t)((icg * 3 + kh) * 3) * 64 + wave * 16;
#pragma unroll
                    for (int kw = 0; kw < 3; kw++) {
                        const float* wp = wrow + kw * 64;       // uniform -> s_load
#pragma unroll
                        for (int o = 0; o < 16; o++) {
                            float wv = wp[o];
                            acc[0][o] = fmaf(iv[kw][0], wv, acc[0][o]);
                            acc[1][o] = fmaf(iv[kw][1], wv, acc[1][o]);
                        }
                    }
                }
            }
        }
        // carry this 72-term fp32 partial into fp64 (same cadence as R4)
#pragma unroll
        for (int j = 0; j < 2; j++)
#pragma unroll
            for (int o = 0; o < 16; o++) {
                accd[j][o] += (double)acc[j][o];
                acc[j][o] = 0.f;
            }
    }

    // bias + relu (fp32-rounded) then pool partial: sum 8 consecutive ow.
#pragma unroll
    for (int o = 0; o < 16; o++) {
        const int oc = wave * 16 + o;
        const double bv = (double)bias[oc];
        double s = (double)fmaxf((float)(accd[0][o] + bv), 0.f)
                 + (double)fmaxf((float)(accd[1][o] + bv), 0.f);
        s += __shfl_xor(s, 1);
        s += __shfl_xor(s, 2);
        if ((lane & 3) == 0)
            tokd[(((size_t)bl * 64 + oc) * 128 + oh) * 16 + (lane >> 2)] = s;
    }
}

// ---------------- attention MLP from pooled tokens (fp64) + fp32-emulated
// sigmoid chain (identical to R3's verified decision rule).
__global__ __launch_bounds__(64) void attn_kernel(
    const double* __restrict__ tokd, const float* __restrict__ aw1,
    const float* __restrict__ ab1, const float* __restrict__ aw2,
    const float* __restrict__ ab2, const float* __restrict__ thrp,
    float* __restrict__ scores, float* __restrict__ maskf, int b0)
{
    const int c  = threadIdx.x;
    const int n  = blockIdx.x;
    const int bl = blockIdx.y;
    const int i = n >> 4, j = n & 15;

    const double* tp = tokd + (((size_t)bl * 64 + c) * 128 + i * 8) * 16 + j;
    double s = 0.0;
#pragma unroll
    for (int p = 0; p < 8; p++) s += tp[p * 16];

    __shared__ double tok[64];
    __shared__ double h[32];
    tok[c] = s * (1.0 / 64.0);
    __syncthreads();
    if (c < 32) {
        double acc = (double)ab1[c];
        for (int k = 0; k < 64; k++) acc += tok[k] * (double)aw1[k * 32 + c];
        h[c] = acc > 0.0 ? acc : 0.0;
    }
    __syncthreads();
    if (c == 0) {
        double logit = (double)ab2[0];
        for (int k = 0; k < 32; k++) logit += h[k] * (double)aw2[k];
        float lf = (float)logit;
        float e1 = (float)exp(-(double)lf);
        float d1 = 1.0f + e1;
        float sc = (float)(1.0 / (double)d1);
        float t  = sc - thrp[0];
        float e2 = (float)exp(-(double)t);
        float d2 = 1.0f + e2;
        float soft = (float)(1.0 / (double)d2);
        scores[(size_t)(b0 + bl) * 256 + n] = sc;
        maskf[(size_t)(b0 + bl) * 256 + n] = (soft > 0.5f) ? 1.f : 0.f;
    }
}

// ---------------- per-batch score sum
__global__ __launch_bounds__(256) void wsum_kernel(
    const float* __restrict__ scores, float* __restrict__ wsum)
{
    int b = blockIdx.x, t = threadIdx.x;
    float v = scores[b * 256 + t];
#pragma unroll
    for (int o = 32; o > 0; o >>= 1) v += __shfl_down(v, o);
    __shared__ float ls[4];
    if ((t & 63) == 0) ls[t >> 6] = v;
    __syncthreads();
    if (t == 0) wsum[b] = (ls[0] + ls[1] + ls[2] + ls[3]) + 1e-6f;
}

// ---------------- patches -> split bf16 hi/lo planes (one pass)
__global__ __launch_bounds__(256) void asplit_kernel(
    const float* __restrict__ A, unsigned short* __restrict__ Ah,
    unsigned short* __restrict__ Al)
{
    size_t i = ((size_t)blockIdx.x * 256 + threadIdx.x) * 8;
    float4 x0 = *(const float4*)(A + i);
    float4 x1 = *(const float4*)(A + i + 4);
    float xv[8] = {x0.x, x0.y, x0.z, x0.w, x1.x, x1.y, x1.z, x1.w};
    unsigned hw[4], lw[4];
#pragma unroll
    for (int q = 0; q < 4; q++) {
        unsigned short h0 = f2bf(xv[2 * q]), h1 = f2bf(xv[2 * q + 1]);
        hw[q] = pk(h0, h1);
        lw[q] = pk(f2bf(xv[2 * q] - bf2f(h0)), f2bf(xv[2 * q + 1] - bf2f(h1)));
    }
    *(uint4*)(Ah + i) = make_uint4(hw[0], hw[1], hw[2], hw[3]);
    *(uint4*)(Al + i) = make_uint4(lw[0], lw[1], lw[2], lw[3]);
}

// ---------------- weight prep: pack W (KxN fp32) into MFMA fragment layout,
// split bf16 hi/lo: Wp[nt][kt][sub][h][lane][8]
__global__ __launch_bounds__(256) void wprep(
    const float* __restrict__ W, unsigned short* __restrict__ Wp, int K, int N, int Npad)
{
    int idx = blockIdx.x * 256 + threadIdx.x;
    int KT = K >> 5;
    int total = (Npad >> 6) * KT * 4 * 64;
    if (idx >= total) return;
    int lane = idx & 63;
    int sub  = (idx >> 6) & 3;
    int t    = idx >> 8;
    int kt = t % KT, nt = t / KT;
    int n  = nt * 64 + sub * 16 + (lane & 15);
    int k0 = kt * 32 + (lane >> 4) * 8;
    unsigned hw[4], lw[4];
#pragma unroll
    for (int q = 0; q < 4; q++) {
        float x0 = (n < N) ? W[(size_t)(k0 + 2 * q) * N + n] : 0.f;
        float x1 = (n < N) ? W[(size_t)(k0 + 2 * q + 1) * N + n] : 0.f;
        unsigned short h0 = f2bf(x0), h1 = f2bf(x1);
        hw[q] = pk(h0, h1);
        lw[q] = pk(f2bf(x0 - bf2f(h0)), f2bf(x1 - bf2f(h1)));
    }
    size_t base = ((((size_t)(nt * KT + kt) * 4 + sub) * 2) * 64 + lane) * 8;
    *(uint4*)(Wp + base)       = make_uint4(hw[0], hw[1], hw[2], hw[3]);
    *(uint4*)(Wp + base + 512) = make_uint4(lw[0], lw[1], lw[2], lw[3]);
}

// det head weights: concat cls_w (256x80) | reg_w (256x4), pad to 128 cols
__global__ __launch_bounds__(256) void wprep_det(
    const float* __restrict__ Wc, const float* __restrict__ Wr,
    unsigned short* __restrict__ Wp)
{
    int idx = blockIdx.x * 256 + threadIdx.x;
    const int KT = 8;
    int total = 2 * KT * 4 * 64;
    if (idx >= total) return;
    int lane = idx & 63;
    int sub  = (idx >> 6) & 3;
    int t    = idx >> 8;
    int kt = t % KT, nt = t / KT;
    int n  = nt * 64 + sub * 16 + (lane & 15);
    int k0 = kt * 32 + (lane >> 4) * 8;
    unsigned hw[4], lw[4];
#pragma unroll
    for (int q = 0; q < 4; q++) {
        int ka = k0 + 2 * q, kb = k0 + 2 * q + 1;
        float x0 = (n < 80) ? Wc[(size_t)ka * 80 + n] : (n < 84 ? Wr[(size_t)ka * 4 + n - 80] : 0.f);
        float x1 = (n < 80) ? Wc[(size_t)kb * 80 + n] : (n < 84 ? Wr[(size_t)kb * 4 + n - 80] : 0.f);
        unsigned short h0 = f2bf(x0), h1 = f2bf(x1);
        hw[q] = pk(h0, h1);
        lw[q] = pk(f2bf(x0 - bf2f(h0)), f2bf(x1 - bf2f(h1)));
    }
    size_t base = ((((size_t)(nt * KT + kt) * 4 + sub) * 2) * 64 + lane) * 8;
    *(uint4*)(Wp + base)       = make_uint4(hw[0], hw[1], hw[2], hw[3]);
    *(uint4*)(Wp + base + 512) = make_uint4(lw[0], lw[1], lw[2], lw[3]);
}

// ---------------- split-bf16 MFMA GEMM: C = epi(A @ W + bias)
// Tile 128(M) x 64(N) x 32(K); 4 waves, each 32 rows x 64 cols (8 C-tiles).
// ASRC: 0 = fp32 A (convert in LDS staging); 1 = pre-split A, DIRECT fragment
//       loads from global (no LDS, no barriers — each wave owns its rows and
//       row-major split planes ARE fragment order);
//       2 = concat: kt<8 -> g fp32 (row m>>8, width 256); kt>=8 -> comb split (width 128)
// ACT: 1 = relu. MASK: 0 none / 1 keep(mask==1) / 2 keep(mask==0).
// OUTF: bit0 fp32 C, bit1 split Ch/Cl. EPID: 1 = detection dual-store.
// Blocks are XCD-swizzled (R6): panel-sharing blocks land on one XCD's L2.
template <int ASRC, int ACT, int MASK, int OUTF, int EPID>
__global__ __launch_bounds__(256) void mgemm(
    const float* __restrict__ Af, const unsigned short* __restrict__ Ahg,
    const unsigned short* __restrict__ Alg, const unsigned short* __restrict__ Wp,
    const float* __restrict__ bias, float* __restrict__ Cf,
    unsigned short* __restrict__ Ch, unsigned short* __restrict__ Cl,
    const float* __restrict__ maskf, int K, int N, int KT,
    float* __restrict__ o80, float* __restrict__ o4,
    const float* __restrict__ clsb, const float* __restrict__ regb)
{
    const int tid  = threadIdx.x;
    const int wave = tid >> 6, lane = tid & 63;
    const int quad = lane >> 4, l16 = lane & 15;

    // ---- bijective XCD swizzle (grid is (NX, 64), NX in {1,2,4,8}) ----
    const int NX   = gridDim.x;
    const int lb   = blockIdx.y * NX + blockIdx.x;   // HW dispatch order, x fastest
    const int xcd  = lb & 7;                          // lands on this XCD (mod-8 RR)
    const int rest = lb >> 3;
    const int lg   = __popc(NX - 1);
    const int bxl  = rest & (NX - 1);                 // logical N-tile
    const int byl  = ((rest >> lg) << 3) | xcd;       // logical M-panel, same-XCD grouped

    const int m0   = byl * 128;

    f32x4 acc[2][4];
#pragma unroll
    for (int a = 0; a < 2; a++)
#pragma unroll
        for (int b = 0; b < 4; b++) acc[a][b] = (f32x4){0.f, 0.f, 0.f, 0.f};

    if constexpr (ASRC == 1) {
        // ---- direct fragment loads, zero LDS, zero barriers ----
        const int row0 = m0 + wave * 32 + l16;             // mt=0 row
        const unsigned short* pah = Ahg + (size_t)row0 * K + quad * 8;
        const unsigned short* pal = Alg + (size_t)row0 * K + quad * 8;
        const unsigned short* pw  = Wp + ((size_t)bxl * KT * 4 * 2 * 64 + lane) * 8;
        const size_t mtoff = (size_t)16 * K;               // mt=1 row offset

#pragma unroll 2
        for (int kt = 0; kt < KT; kt++) {
            short8 wh[4], wl[4];
#pragma unroll
            for (int s = 0; s < 4; s++) {
                wh[s] = *(const short8*)(pw + (size_t)s * 1024);
                wl[s] = *(const short8*)(pw + (size_t)s * 1024 + 512);
            }
            short8 ah0 = *(const short8*)(pah);
            short8 al0 = *(const short8*)(pal);
            short8 ah1 = *(const short8*)(pah + mtoff);
            short8 al1 = *(const short8*)(pal + mtoff);
#pragma unroll
            for (int s = 0; s < 4; s++) {
                acc[0][s] = __builtin_amdgcn_mfma_f32_16x16x32_bf16(ah0, wh[s], acc[0][s], 0, 0, 0);
                acc[0][s] = __builtin_amdgcn_mfma_f32_16x16x32_bf16(al0, wh[s], acc[0][s], 0, 0, 0);
                acc[0][s] = __builtin_amdgcn_mfma_f32_16x16x32_bf16(ah0, wl[s], acc[0][s], 0, 0, 0);
                acc[1][s] = __builtin_amdgcn_mfma_f32_16x16x32_bf16(ah1, wh[s], acc[1][s], 0, 0, 0);
                acc[1][s] = __builtin_amdgcn_mfma_f32_16x16x32_bf16(al1, wh[s], acc[1][s], 0, 0, 0);
                acc[1][s] = __builtin_amdgcn_mfma_f32_16x16x32_bf16(ah1, wl[s], acc[1][s], 0, 0, 0);
            }
            pah += 32; pal += 32; pw += 4096;
        }
    } else {
        // ---- original LDS-staged loop (ASRC 0 / 2) ----
        __shared__ unsigned short AhL[128 * 40];
        __shared__ unsigned short AlL[128 * 40];
        const int srow = tid >> 1, shalf = tid & 1;

        for (int kt = 0; kt < KT; kt++) {
            {
                const int m  = m0 + srow;
                const int kb = kt * 32 + shalf * 16;
                const int lofs = srow * 40 + shalf * 16;
                bool conv_path;
                if (ASRC == 0) conv_path = true;
                else conv_path = (kt < 8);

                if (conv_path) {
                    const float* ap = (ASRC == 2) ? (Af + (size_t)(m >> 8) * 256 + kb)
                                                  : (Af + (size_t)m * K + kb);
                    float4 x0 = *(const float4*)(ap + 0);
                    float4 x1 = *(const float4*)(ap + 4);
                    float4 x2 = *(const float4*)(ap + 8);
                    float4 x3 = *(const float4*)(ap + 12);
                    float xv[16] = {x0.x, x0.y, x0.z, x0.w, x1.x, x1.y, x1.z, x1.w,
                                    x2.x, x2.y, x2.z, x2.w, x3.x, x3.y, x3.z, x3.w};
                    unsigned hw[8], lw[8];
#pragma unroll
                    for (int q = 0; q < 8; q++) {
                        unsigned short h0 = f2bf(xv[2 * q]), h1 = f2bf(xv[2 * q + 1]);
                        unsigned short l0 = f2bf(xv[2 * q] - bf2f(h0));
                        unsigned short l1 = f2bf(xv[2 * q + 1] - bf2f(h1));
                        hw[q] = pk(h0, h1);
                        lw[q] = pk(l0, l1);
                    }
                    *(uint4*)&AhL[lofs]     = make_uint4(hw[0], hw[1], hw[2], hw[3]);
                    *(uint4*)&AhL[lofs + 8] = make_uint4(hw[4], hw[5], hw[6], hw[7]);
                    *(uint4*)&AlL[lofs]     = make_uint4(lw[0], lw[1], lw[2], lw[3]);
                    *(uint4*)&AlL[lofs + 8] = make_uint4(lw[4], lw[5], lw[6], lw[7]);
                } else {
                    const size_t ro = (ASRC == 2) ? ((size_t)m * 128 + (kb - 256))
                                                  : ((size_t)m * K + kb);
                    uint4 h0 = *(const uint4*)(Ahg + ro);
                    uint4 h1 = *(const uint4*)(Ahg + ro + 8);
                    uint4 l0 = *(const uint4*)(Alg + ro);
                    uint4 l1 = *(const uint4*)(Alg + ro + 8);
                    *(uint4*)&AhL[lofs]     = h0;
                    *(uint4*)&AhL[lofs + 8] = h1;
                    *(uint4*)&AlL[lofs]     = l0;
                    *(uint4*)&AlL[lofs + 8] = l1;
                }
            }
            __syncthreads();

            const unsigned short* wk = Wp + ((size_t)bxl * KT * 4 * 2 * 64 + lane) * 8
                                     + (size_t)kt * (4 * 2 * 64 * 8);
            short8 wh[4], wl[4];
#pragma unroll
            for (int s = 0; s < 4; s++) {
                wh[s] = *(const short8*)(wk + (size_t)s * (2 * 64 * 8));
                wl[s] = *(const short8*)(wk + (size_t)s * (2 * 64 * 8) + 64 * 8);
            }
            short8 ah[2], al[2];
#pragma unroll
            for (int mt = 0; mt < 2; mt++) {
                const int r = wave * 32 + mt * 16 + l16;
                ah[mt] = *(const short8*)&AhL[r * 40 + quad * 8];
                al[mt] = *(const short8*)&AlL[r * 40 + quad * 8];
            }
#pragma unroll
            for (int mt = 0; mt < 2; mt++)
#pragma unroll
                for (int s = 0; s < 4; s++) {
                    acc[mt][s] = __builtin_amdgcn_mfma_f32_16x16x32_bf16(ah[mt], wh[s], acc[mt][s], 0, 0, 0);
                    acc[mt][s] = __builtin_amdgcn_mfma_f32_16x16x32_bf16(al[mt], wh[s], acc[mt][s], 0, 0, 0);
                    acc[mt][s] = __builtin_amdgcn_mfma_f32_16x16x32_bf16(ah[mt], wl[s], acc[mt][s], 0, 0, 0);
                }
            __syncthreads();
        }
    }

    // ---- epilogue
    const int nbase = bxl * 64;
#pragma unroll
    for (int mt = 0; mt < 2; mt++) {
        const int mrow0 = m0 + wave * 32 + mt * 16 + quad * 4;
        float mk[4];
        if (MASK != 0) {
#pragma unroll
            for (int r = 0; r < 4; r++) mk[r] = maskf[mrow0 + r];
        }
#pragma unroll
        for (int s = 0; s < 4; s++) {
            const int n = nbase + s * 16 + l16;
            float bv;
            if (EPID == 1)
                bv = (n < 80) ? clsb[n] : (n < 84 ? regb[n - 80] : 0.f);
            else
                bv = bias[n];
#pragma unroll
            for (int r = 0; r < 4; r++) {
                const int m = mrow0 + r;
                float v = acc[mt][s][r] + bv;
                if (ACT) v = fmaxf(v, 0.f);
                bool st = true;
                if (MASK == 1) st = mk[r] > 0.5f;
                if (MASK == 2) st = mk[r] < 0.5f;
                if (st) {
                    if (OUTF & 1) Cf[(size_t)m * N + n] = v;
                    if (OUTF & 2) {
                        unsigned short hh = f2bf(v);
                        Ch[(size_t)m * N + n] = hh;
                        Cl[(size_t)m * N + n] = f2bf(v - bf2f(hh));
                    }
                    if (EPID == 1) {
                        if (n < 80)      o80[(size_t)m * 80 + n] = v;
                        else if (n < 84) o4[(size_t)m * 4 + (n - 80)] = v;
                    }
                }
            }
        }
    }
}

// ---------------- per-batch pooling of comb: mean & score-weighted
__global__ __launch_bounds__(128) void pool2_kernel(
    const float* __restrict__ comb, const float* __restrict__ scores,
    const float* __restrict__ wsum, float* __restrict__ meanp,
    float* __restrict__ attnp)
{
    int b = blockIdx.x, d = threadIdx.x;
    float ms = 0.f, as = 0.f;
    for (int n = 0; n < 256; n++) {
        float v = comb[((size_t)b * 256 + n) * 128 + d];
        ms += v;
        as = fmaf(scores[b * 256 + n], v, as);
    }
    meanp[b * 128 + d] = ms * (1.f / 256.f);
    attnp[b * 128 + d] = as / wsum[b];
}

// ---------------- aggregator
__global__ __launch_bounds__(256) void agg_kernel(
    const float* __restrict__ meanp, const float* __restrict__ attnp,
    const float* __restrict__ gw, const float* __restrict__ gb,
    float* __restrict__ g)
{
    int b = blockIdx.x, j = threadIdx.x;
    __shared__ float cat[256];
    cat[j] = (j < 128) ? meanp[b * 128 + j] : attnp[b * 128 + j - 128];
    __syncthreads();
    float acc = gb[j];
    for (int k = 0; k < 256; k++) acc = fmaf(cat[k], gw[k * 256 + j], acc);
    g[b * 256 + j] = acc > 0.f ? acc : 0.f;
}

// ---------------------------------------------------------------------------
extern "C" void kernel_launch(void* const* d_in, const int* in_sizes, int n_in,
                              void* d_out, int out_size, void* d_ws, size_t ws_size,
                              hipStream_t stream)
{
    (void)in_sizes; (void)n_in; (void)out_size;

    const float* images = (const float*)d_in[0];
    const float* patches = (const float*)d_in[1];
    const float* cw1 = (const float*)d_in[2];
    const float* cb1 = (const float*)d_in[3];
    const float* cw2 = (const float*)d_in[4];
    const float* cb2 = (const float*)d_in[5];
    const float* aw1 = (const float*)d_in[6];
    const float* ab1 = (const float*)d_in[7];
    const float* aw2 = (const float*)d_in[8];
    const float* ab2 = (const float*)d_in[9];
    const float* thr = (const float*)d_in[10];
    const float* bw1 = (const float*)d_in[11];
    const float* bb1 = (const float*)d_in[12];
    const float* bw2 = (const float*)d_in[13];
    const float* bb2 = (const float*)d_in[14];
    const float* bw3 = (const float*)d_in[15];
    const float* bb3 = (const float*)d_in[16];
    const float* bw4 = (const float*)d_in[17];
    const float* bb4 = (const float*)d_in[18];
    const float* sw1 = (const float*)d_in[19];
    const float* sb1 = (const float*)d_in[20];
    const float* sw2 = (const float*)d_in[21];
    const float* sb2 = (const float*)d_in[22];
    const float* gw  = (const float*)d_in[23];
    const float* gb  = (const float*)d_in[24];
    const float* dw1 = (const float*)d_in[25];
    const float* db1 = (const float*)d_in[26];
    const float* cls_w = (const float*)d_in[27];
    const float* cls_b = (const float*)d_in[28];
    const float* reg_w = (const float*)d_in[29];
    const float* reg_b = (const float*)d_in[30];
    float* out = (float*)d_out;
    float* o80 = out;
    float* o4  = out + 655360;

    // ---- workspace carve-up (bytes, 256-aligned)
    unsigned char* base = (unsigned char*)d_ws;
    size_t off = 0;
    auto alloc = [&](size_t bytes) -> unsigned char* {
        unsigned char* r = base + off;
        off += (bytes + 255) & ~(size_t)255;
        return r;
    };

    // fixed-size buffers first
    float*  scores = (float*)alloc(8192 * 4);
    float*  maskf  = (float*)alloc(8192 * 4);
    float*  wsumb  = (float*)alloc(32 * 4);
    float*  combf  = (float*)alloc((size_t)8192 * 128 * 4);
    float*  meanp  = (float*)alloc(4096 * 4);
    float*  attnp  = (float*)alloc(4096 * 4);
    float*  gbuf   = (float*)alloc(8192 * 4);
    float*  wtc2   = (float*)alloc((size_t)64 * 9 * 64 * 4);   // conv2 transposed weights

    typedef unsigned short ush;
    ush* wp_bw1 = (ush*)alloc((size_t)8 * 96 * 4096 * 2);
    ush* wp_bw2 = (ush*)alloc((size_t)8 * 16 * 4096 * 2);
    ush* wp_bw3 = (ush*)alloc((size_t)8 * 16 * 4096 * 2);
    ush* wp_bw4 = (ush*)alloc((size_t)2 * 16 * 4096 * 2);
    ush* wp_sw1 = (ush*)alloc((size_t)1 * 96 * 4096 * 2);
    ush* wp_sw2 = (ush*)alloc((size_t)2 * 2 * 4096 * 2);
    ush* wp_dw1 = (ush*)alloc((size_t)4 * 12 * 4096 * 2);
    ush* wp_det = (ush*)alloc((size_t)2 * 8 * 4096 * 2);

    ush* hb1h = (ush*)alloc((size_t)8192 * 512 * 2);
    ush* hb1l = (ush*)alloc((size_t)8192 * 512 * 2);
    ush* hb2h = (ush*)alloc((size_t)8192 * 512 * 2);
    ush* hb2l = (ush*)alloc((size_t)8192 * 512 * 2);
    ush* hb3h = (ush*)alloc((size_t)8192 * 512 * 2);
    ush* hb3l = (ush*)alloc((size_t)8192 * 512 * 2);
    ush* hsh  = (ush*)alloc((size_t)8192 * 64 * 2);
    ush* hsl  = (ush*)alloc((size_t)8192 * 64 * 2);
    ush* combh = (ush*)alloc((size_t)8192 * 128 * 2);
    ush* combl = (ush*)alloc((size_t)8192 * 128 * 2);
    ush* hdh  = (ush*)alloc((size_t)8192 * 256 * 2);
    ush* hdl  = (ush*)alloc((size_t)8192 * 256 * 2);

    // slice-sized buffers: x1 + tokd
    size_t remain = (ws_size > off) ? (ws_size - off) : 0;
    int SL = 8;
    while (SL > 1) {
        size_t need = (size_t)SL * 64 * 256 * 256 * 4 + (size_t)SL * 64 * 128 * 16 * 8 + 1024;
        if (need <= remain) break;
        SL >>= 1;
    }
    float*  x1   = (float*)alloc((size_t)SL * 64 * 256 * 256 * 4);
    double* tokd = (double*)alloc((size_t)SL * 64 * 128 * 16 * 8);

    // patches split buffers: alias the (dead after conv loop) x1 region when it
    // is big enough (SL=8: 134MB >= 100.7MB), else dedicated alloc, else fall
    // back to the in-staging conversion path.
    const size_t ps_bytes = (size_t)8192 * 3072 * 2;   // 50.33 MB per plane
    ush* psh = nullptr;
    ush* psl = nullptr;
    int have_split = 0;
    if ((size_t)SL * 64 * 256 * 256 * 4 >= 2 * ps_bytes) {
        psh = (ush*)x1;
        psl = (ush*)((unsigned char*)x1 + ps_bytes);
        have_split = 1;
    } else {
        size_t rem2 = (ws_size > off) ? (ws_size - off) : 0;
        if (rem2 >= 2 * ps_bytes + 1024) {
            psh = (ush*)alloc(ps_bytes);
            psl = (ush*)alloc(ps_bytes);
            have_split = 1;
        }
    }

    // ---- weight preps
    {
        wprep_conv2<<<(64 * 9 * 64 + 255) / 256, 256, 0, stream>>>(cw2, wtc2);
        int t1 = 8 * 96 * 4 * 64;  wprep<<<(t1 + 255) / 256, 256, 0, stream>>>(bw1, wp_bw1, 3072, 512, 512);
        int t2 = 8 * 16 * 4 * 64;  wprep<<<(t2 + 255) / 256, 256, 0, stream>>>(bw2, wp_bw2, 512, 512, 512);
                                   wprep<<<(t2 + 255) / 256, 256, 0, stream>>>(bw3, wp_bw3, 512, 512, 512);
        int t4 = 2 * 16 * 4 * 64;  wprep<<<(t4 + 255) / 256, 256, 0, stream>>>(bw4, wp_bw4, 512, 128, 128);
        int t5 = 1 * 96 * 4 * 64;  wprep<<<(t5 + 255) / 256, 256, 0, stream>>>(sw1, wp_sw1, 3072, 64, 64);
        int t6 = 2 * 2 * 4 * 64;   wprep<<<(t6 + 255) / 256, 256, 0, stream>>>(sw2, wp_sw2, 64, 128, 128);
        int t7 = 4 * 12 * 4 * 64;  wprep<<<(t7 + 255) / 256, 256, 0, stream>>>(dw1, wp_dw1, 384, 256, 256);
        int t8 = 2 * 8 * 4 * 64;   wprep_det<<<(t8 + 255) / 256, 256, 0, stream>>>(cls_w, reg_w, wp_det);
    }

    // ---- backbone + attention scores, batch-sliced
    for (int s = 0; s < B_ALL / SL; s++) {
        conv1_kernel<<<dim3(256, SL), 256, 0, stream>>>(images, cw1, cb1, x1, s * SL);
        conv2_kernel<<<dim3(128, SL), 256, 0, stream>>>(x1, wtc2, cb2, tokd);
        attn_kernel<<<dim3(256, SL), 64, 0, stream>>>(tokd, aw1, ab1, aw2, ab2,
                                                      thr, scores, maskf, s * SL);
    }
    wsum_kernel<<<32, 256, 0, stream>>>(scores, wsumb);

    // ---- experts (split-bf16 MFMA)
    if (have_split) {
        asplit_kernel<<<(8192 * 3072) / (8 * 256), 256, 0, stream>>>(patches, psh, psl);
        mgemm<1, 1, 0, 2, 0><<<dim3(8, 64), 256, 0, stream>>>(
            nullptr, psh, psl, wp_bw1, bb1, nullptr, hb1h, hb1l, nullptr,
            3072, 512, 96, nullptr, nullptr, nullptr, nullptr);
        mgemm<1, 1, 0, 2, 0><<<dim3(1, 64), 256, 0, stream>>>(
            nullptr, psh, psl, wp_sw1, sb1, nullptr, hsh, hsl, nullptr,
            3072, 64, 96, nullptr, nullptr, nullptr, nullptr);
    } else {
        mgemm<0, 1, 0, 2, 0><<<dim3(8, 64), 256, 0, stream>>>(
            patches, nullptr, nullptr, wp_bw1, bb1, nullptr, hb1h, hb1l, nullptr,
            3072, 512, 96, nullptr, nullptr, nullptr, nullptr);
        mgemm<0, 1, 0, 2, 0><<<dim3(1, 64), 256, 0, stream>>>(
            patches, nullptr, nullptr, wp_sw1, sb1, nullptr, hsh, hsl, nullptr,
            3072, 64, 96, nullptr, nullptr, nullptr, nullptr);
    }
    mgemm<1, 1, 0, 2, 0><<<dim3(8, 64), 256, 0, stream>>>(
        nullptr, hb1h, hb1l, wp_bw2, bb2, nullptr, hb2h, hb2l, nullptr,
        512, 512, 16, nullptr, nullptr, nullptr, nullptr);
    mgemm<1, 1, 0, 2, 0><<<dim3(8, 64), 256, 0, stream>>>(
        nullptr, hb2h, hb2l, wp_bw3, bb3, nullptr, hb3h, hb3l, nullptr,
        512, 512, 16, nullptr, nullptr, nullptr, nullptr);
    mgemm<1, 0, 1, 3, 0><<<dim3(2, 64), 256, 0, stream>>>(
        nullptr, hb3h, hb3l, wp_bw4, bb4, combf, combh, combl, maskf,
        512, 128, 16, nullptr, nullptr, nullptr, nullptr);
    mgemm<1, 0, 2, 3, 0><<<dim3(2, 64), 256, 0, stream>>>(
        nullptr, hsh, hsl, wp_sw2, sb2, combf, combh, combl, maskf,
        64, 128, 2, nullptr, nullptr, nullptr, nullptr);

    // ---- aggregate + detection
    pool2_kernel<<<32, 128, 0, stream>>>(combf, scores, wsumb, meanp, attnp);
    agg_kernel<<<32, 256, 0, stream>>>(meanp, attnp, gw, gb, gbuf);
    mgemm<2, 1, 0, 2, 0><<<dim3(4, 64), 256, 0, stream>>>(
        gbuf, combh, combl, wp_dw1, db1, nullptr, hdh, hdl, nullptr,
        384, 256, 12, nullptr, nullptr, nullptr, nullptr);
    mgemm<1, 0, 0, 0, 1><<<dim3(2, 64), 256, 0, stream>>>(
        nullptr, hdh, hdl, wp_det, nullptr, nullptr, nullptr, nullptr, nullptr,
        256, 128, 8, o80, o4, cls_b, reg_b);
}

// Round 3
// 1355.411 us; speedup vs baseline: 1.0474x; 1.0474x over previous
//
#include <hip/hip_runtime.h>
#include <math.h>

// ---------------------------------------------------------------------------
// AttentionRoutingDetector — R8: fragment-tiled A storage + 2-deep pipelined
// direct-load GEMM. R7 removed LDS but its A-fragment loads were scattered
// (16 rows x 16B per wave-load -> ~16 transactions each); MfmaUtil dropped.
// Now every A-operand producer (asplit, mgemm epilogues) writes the split
// planes in MFMA-fragment order, so each A-fragment load is ONE coalesced
// 1KB wave transaction (same as W). The ASRC=1 K-loop is explicitly
// software-pipelined 2-deep with named register sets — loads of kt+1 in
// flight under MFMAs of kt, no barriers anywhere. Values and MFMA order are
// bit-identical to R5/R6/R7. Router/conv path untouched.
// ---------------------------------------------------------------------------

#define B_ALL 32

typedef __attribute__((ext_vector_type(8))) short short8;
typedef __attribute__((ext_vector_type(4))) float f32x4;

__device__ __forceinline__ unsigned short f2bf(float x) {
    unsigned u = __float_as_uint(x);
    return (unsigned short)((u + 0x7FFFu + ((u >> 16) & 1u)) >> 16);
}
__device__ __forceinline__ float bf2f(unsigned short h) {
    return __uint_as_float(((unsigned)h) << 16);
}
__device__ __forceinline__ unsigned pk(unsigned short a, unsigned short b) {
    return (unsigned)a | ((unsigned)b << 16);
}

// fragment-tiled address for split A/C planes: element (m, k) of a matrix
// whose K-dim tile count is KTn (= K/32). Lane-contiguous per (16-row,32-k) tile.
__device__ __forceinline__ size_t fragaddr(int m, int n, int KTn) {
    return ((size_t)((m >> 4) * KTn + (n >> 5)) * 4 + ((n & 31) >> 3)) * 128
           + (size_t)(m & 15) * 8 + (n & 7);
}

// ---------------- conv1: (b,3,512,512) -> relu -> (b,64,256,256), stride 2
__global__ __launch_bounds__(256) void conv1_kernel(
    const float* __restrict__ img, const float* __restrict__ w,
    const float* __restrict__ bias, float* __restrict__ x1, int b0)
{
    const int ow = threadIdx.x;
    const int oh = blockIdx.x;
    const int bl = blockIdx.y;
    const int b  = b0 + bl;

    const float* ib = img + (size_t)b * 3 * 512 * 512;
    float in[3][3][3];
#pragma unroll
    for (int c = 0; c < 3; c++)
#pragma unroll
        for (int kh = 0; kh < 3; kh++) {
            int ih = oh * 2 + kh;
#pragma unroll
            for (int kw = 0; kw < 3; kw++) {
                int iw = ow * 2 + kw;
                in[c][kh][kw] = (ih < 512 && iw < 512)
                    ? ib[((size_t)c * 512 + ih) * 512 + iw] : 0.f;
            }
        }

    float* ob = x1 + ((size_t)bl * 64 * 256 + oh) * 256 + ow;
#pragma unroll 2
    for (int oc = 0; oc < 64; oc++) {
        const float* wp = w + oc * 27;
        float p[3] = {0.f, 0.f, 0.f};
#pragma unroll
        for (int c = 0; c < 3; c++)
#pragma unroll
            for (int kh = 0; kh < 3; kh++)
#pragma unroll
                for (int kw = 0; kw < 3; kw++)
                    p[c] = fmaf(in[c][kh][kw], wp[(c * 3 + kh) * 3 + kw], p[c]);
        double s = (double)bias[oc] + ((double)p[0] + (double)p[1] + (double)p[2]);
        float r = (float)s;
        ob[(size_t)oc * 256 * 256] = r > 0.f ? r : 0.f;
    }
}

// ---------------- conv2 weight transpose: w[oc][ic][kh][kw] -> wt[ic][kh][kw][oc]
__global__ __launch_bounds__(256) void wprep_conv2(
    const float* __restrict__ w, float* __restrict__ wt)
{
    int idx = blockIdx.x * 256 + threadIdx.x;
    if (idx >= 64 * 9 * 64) return;
    int oc = idx & 63;
    int r  = idx >> 6;          // ic*9 + kh*3 + kw
    wt[r * 64 + oc] = w[(size_t)oc * 576 + r];
}

// ---------------- conv2 + fused 8x8 pool partials (no LDS, no barriers).
__global__ __launch_bounds__(256, 3) void conv2_kernel(
    const float* __restrict__ x1, const float* __restrict__ wt,
    const float* __restrict__ bias, double* __restrict__ tokd)
{
    const int tid  = threadIdx.x;
    const int lane = tid & 63;
    const int wave = __builtin_amdgcn_readfirstlane(tid >> 6);   // 0..3, scalar
    const int oh   = blockIdx.x;          // 0..127
    const int bl   = blockIdx.y;
    const int ow0  = lane * 2;            // this thread: ow0, ow0+1

    const float* xb = x1 + (size_t)bl * 64 * 256 * 256;

    float  acc[2][16];
    double accd[2][16];
#pragma unroll
    for (int j = 0; j < 2; j++)
#pragma unroll
        for (int o = 0; o < 16; o++) { acc[j][o] = 0.f; accd[j][o] = 0.0; }

    for (int ic0 = 0; ic0 < 64; ic0 += 8) {
#pragma unroll 2
        for (int ic = 0; ic < 8; ic++) {
            const int icg = ic0 + ic;
#pragma unroll
            for (int kh = 0; kh < 3; kh++) {
                const int ih = oh * 2 + kh;
                if (ih < 256) {
                    const float* rp = xb + ((size_t)icg * 256 + ih) * 256 + ow0 * 2;
                    float4 f4 = *(const float4*)rp;            // cols 4L..4L+3
                    float  f5 = (ow0 < 126) ? rp[4] : 0.f;     // col 4L+4 (lane63 OOB=0)
                    float iv[3][2] = {{f4.x, f4.z}, {f4.y, f4.w}, {f4.z, f5}};
                    const float* wrow = wt + (size_t)((icg * 3 + kh) * 3) * 64 + wave * 16;
#pragma unroll
                    for (int kw = 0; kw < 3; kw++) {
                        const float* wp = wrow + kw * 64;       // uniform -> s_load
#pragma unroll
                        for (int o = 0; o < 16; o++) {
                            float wv = wp[o];
                            acc[0][o] = fmaf(iv[kw][0], wv, acc[0][o]);
                            acc[1][o] = fmaf(iv[kw][1], wv, acc[1][o]);
                        }
                    }
                }
            }
        }
        // carry this 72-term fp32 partial into fp64 (same cadence as R4)
#pragma unroll
        for (int j = 0; j < 2; j++)
#pragma unroll
            for (int o = 0; o < 16; o++) {
                accd[j][o] += (double)acc[j][o];
                acc[j][o] = 0.f;
            }
    }

    // bias + relu (fp32-rounded) then pool partial: sum 8 consecutive ow.
#pragma unroll
    for (int o = 0; o < 16; o++) {
        const int oc = wave * 16 + o;
        const double bv = (double)bias[oc];
        double s = (double)fmaxf((float)(accd[0][o] + bv), 0.f)
                 + (double)fmaxf((float)(accd[1][o] + bv), 0.f);
        s += __shfl_xor(s, 1);
        s += __shfl_xor(s, 2);
        if ((lane & 3) == 0)
            tokd[(((size_t)bl * 64 + oc) * 128 + oh) * 16 + (lane >> 2)] = s;
    }
}

// ---------------- attention MLP from pooled tokens (fp64) + fp32-emulated
// sigmoid chain (identical to R3's verified decision rule).
__global__ __launch_bounds__(64) void attn_kernel(
    const double* __restrict__ tokd, const float* __restrict__ aw1,
    const float* __restrict__ ab1, const float* __restrict__ aw2,
    const float* __restrict__ ab2, const float* __restrict__ thrp,
    float* __restrict__ scores, float* __restrict__ maskf, int b0)
{
    const int c  = threadIdx.x;
    const int n  = blockIdx.x;
    const int bl = blockIdx.y;
    const int i = n >> 4, j = n & 15;

    const double* tp = tokd + (((size_t)bl * 64 + c) * 128 + i * 8) * 16 + j;
    double s = 0.0;
#pragma unroll
    for (int p = 0; p < 8; p++) s += tp[p * 16];

    __shared__ double tok[64];
    __shared__ double h[32];
    tok[c] = s * (1.0 / 64.0);
    __syncthreads();
    if (c < 32) {
        double acc = (double)ab1[c];
        for (int k = 0; k < 64; k++) acc += tok[k] * (double)aw1[k * 32 + c];
        h[c] = acc > 0.0 ? acc : 0.0;
    }
    __syncthreads();
    if (c == 0) {
        double logit = (double)ab2[0];
        for (int k = 0; k < 32; k++) logit += h[k] * (double)aw2[k];
        float lf = (float)logit;
        float e1 = (float)exp(-(double)lf);
        float d1 = 1.0f + e1;
        float sc = (float)(1.0 / (double)d1);
        float t  = sc - thrp[0];
        float e2 = (float)exp(-(double)t);
        float d2 = 1.0f + e2;
        float soft = (float)(1.0 / (double)d2);
        scores[(size_t)(b0 + bl) * 256 + n] = sc;
        maskf[(size_t)(b0 + bl) * 256 + n] = (soft > 0.5f) ? 1.f : 0.f;
    }
}

// ---------------- per-batch score sum
__global__ __launch_bounds__(256) void wsum_kernel(
    const float* __restrict__ scores, float* __restrict__ wsum)
{
    int b = blockIdx.x, t = threadIdx.x;
    float v = scores[b * 256 + t];
#pragma unroll
    for (int o = 32; o > 0; o >>= 1) v += __shfl_down(v, o);
    __shared__ float ls[4];
    if ((t & 63) == 0) ls[t >> 6] = v;
    __syncthreads();
    if (t == 0) wsum[b] = (ls[0] + ls[1] + ls[2] + ls[3]) + 1e-6f;
}

// ---------------- patches -> split bf16 hi/lo planes, FRAGMENT-TILED.
// Thread g: tile = g>>6 (rt*96+kt), lane l = g&63 -> m = rt*16+(l&15),
// k0 = kt*32+(l>>4)*8. Stores are lane-contiguous 16B -> fully coalesced.
// Values identical to before: hi=f2bf(x), lo=f2bf(x-bf2f(hi)).
__global__ __launch_bounds__(256) void asplit_kernel(
    const float* __restrict__ A, unsigned short* __restrict__ Ah,
    unsigned short* __restrict__ Al)
{
    const size_t g = (size_t)blockIdx.x * 256 + threadIdx.x;
    const int tile = (int)(g >> 6);
    const int l    = (int)(g & 63);
    const int rt = tile / 96, kt = tile % 96;
    const int m  = rt * 16 + (l & 15);
    const int k0 = kt * 32 + (l >> 4) * 8;

    const float* ap = A + (size_t)m * 3072 + k0;
    float4 x0 = *(const float4*)(ap);
    float4 x1 = *(const float4*)(ap + 4);
    float xv[8] = {x0.x, x0.y, x0.z, x0.w, x1.x, x1.y, x1.z, x1.w};
    unsigned hw[4], lw[4];
#pragma unroll
    for (int q = 0; q < 4; q++) {
        unsigned short h0 = f2bf(xv[2 * q]), h1 = f2bf(xv[2 * q + 1]);
        hw[q] = pk(h0, h1);
        lw[q] = pk(f2bf(xv[2 * q] - bf2f(h0)), f2bf(xv[2 * q + 1] - bf2f(h1)));
    }
    *(uint4*)(Ah + g * 8) = make_uint4(hw[0], hw[1], hw[2], hw[3]);
    *(uint4*)(Al + g * 8) = make_uint4(lw[0], lw[1], lw[2], lw[3]);
}

// ---------------- weight prep: pack W (KxN fp32) into MFMA fragment layout,
// split bf16 hi/lo: Wp[nt][kt][sub][h][lane][8]
__global__ __launch_bounds__(256) void wprep(
    const float* __restrict__ W, unsigned short* __restrict__ Wp, int K, int N, int Npad)
{
    int idx = blockIdx.x * 256 + threadIdx.x;
    int KT = K >> 5;
    int total = (Npad >> 6) * KT * 4 * 64;
    if (idx >= total) return;
    int lane = idx & 63;
    int sub  = (idx >> 6) & 3;
    int t    = idx >> 8;
    int kt = t % KT, nt = t / KT;
    int n  = nt * 64 + sub * 16 + (lane & 15);
    int k0 = kt * 32 + (lane >> 4) * 8;
    unsigned hw[4], lw[4];
#pragma unroll
    for (int q = 0; q < 4; q++) {
        float x0 = (n < N) ? W[(size_t)(k0 + 2 * q) * N + n] : 0.f;
        float x1 = (n < N) ? W[(size_t)(k0 + 2 * q + 1) * N + n] : 0.f;
        unsigned short h0 = f2bf(x0), h1 = f2bf(x1);
        hw[q] = pk(h0, h1);
        lw[q] = pk(f2bf(x0 - bf2f(h0)), f2bf(x1 - bf2f(h1)));
    }
    size_t base = ((((size_t)(nt * KT + kt) * 4 + sub) * 2) * 64 + lane) * 8;
    *(uint4*)(Wp + base)       = make_uint4(hw[0], hw[1], hw[2], hw[3]);
    *(uint4*)(Wp + base + 512) = make_uint4(lw[0], lw[1], lw[2], lw[3]);
}

// det head weights: concat cls_w (256x80) | reg_w (256x4), pad to 128 cols
__global__ __launch_bounds__(256) void wprep_det(
    const float* __restrict__ Wc, const float* __restrict__ Wr,
    unsigned short* __restrict__ Wp)
{
    int idx = blockIdx.x * 256 + threadIdx.x;
    const int KT = 8;
    int total = 2 * KT * 4 * 64;
    if (idx >= total) return;
    int lane = idx & 63;
    int sub  = (idx >> 6) & 3;
    int t    = idx >> 8;
    int kt = t % KT, nt = t / KT;
    int n  = nt * 64 + sub * 16 + (lane & 15);
    int k0 = kt * 32 + (lane >> 4) * 8;
    unsigned hw[4], lw[4];
#pragma unroll
    for (int q = 0; q < 4; q++) {
        int ka = k0 + 2 * q, kb = k0 + 2 * q + 1;
        float x0 = (n < 80) ? Wc[(size_t)ka * 80 + n] : (n < 84 ? Wr[(size_t)ka * 4 + n - 80] : 0.f);
        float x1 = (n < 80) ? Wc[(size_t)kb * 80 + n] : (n < 84 ? Wr[(size_t)kb * 4 + n - 80] : 0.f);
        unsigned short h0 = f2bf(x0), h1 = f2bf(x1);
        hw[q] = pk(h0, h1);
        lw[q] = pk(f2bf(x0 - bf2f(h0)), f2bf(x1 - bf2f(h1)));
    }
    size_t base = ((((size_t)(nt * KT + kt) * 4 + sub) * 2) * 64 + lane) * 8;
    *(uint4*)(Wp + base)       = make_uint4(hw[0], hw[1], hw[2], hw[3]);
    *(uint4*)(Wp + base + 512) = make_uint4(lw[0], lw[1], lw[2], lw[3]);
}

// ---------------- split-bf16 MFMA GEMM: C = epi(A @ W + bias)
// Tile 128(M) x 64(N) x 32(K); 4 waves, each 32 rows x 64 cols (8 C-tiles).
// ASRC: 0 = fp32 A row-major (convert in LDS staging);
//       1 = pre-split A in FRAGMENT-TILED layout, direct coalesced loads,
//           2-deep software pipeline, zero LDS / zero barriers;
//       2 = concat: kt<8 -> g fp32 via LDS (row m>>8, width 256);
//           kt>=8 -> comb split fragment-tiled, direct loads.
// ACT: 1 = relu. MASK: 0 none / 1 keep(mask==1) / 2 keep(mask==0).
// OUTF: bit0 fp32 C row-major, bit1 split Ch/Cl FRAGMENT-TILED (KTn = N/32).
// EPID: 1 = detection dual-store. XCD swizzle (R6) retained.
template <int ASRC, int ACT, int MASK, int OUTF, int EPID>
__global__ __launch_bounds__(256, 2) void mgemm(
    const float* __restrict__ Af, const unsigned short* __restrict__ Ahg,
    const unsigned short* __restrict__ Alg, const unsigned short* __restrict__ Wp,
    const float* __restrict__ bias, float* __restrict__ Cf,
    unsigned short* __restrict__ Ch, unsigned short* __restrict__ Cl,
    const float* __restrict__ maskf, int K, int N, int KT,
    float* __restrict__ o80, float* __restrict__ o4,
    const float* __restrict__ clsb, const float* __restrict__ regb)
{
    const int tid  = threadIdx.x;
    const int wave = tid >> 6, lane = tid & 63;
    const int quad = lane >> 4, l16 = lane & 15;

    // ---- bijective XCD swizzle (grid is (NX, 64), NX in {1,2,4,8}) ----
    const int NX   = gridDim.x;
    const int lb   = blockIdx.y * NX + blockIdx.x;   // HW dispatch order, x fastest
    const int xcd  = lb & 7;                          // lands on this XCD (mod-8 RR)
    const int rest = lb >> 3;
    const int lg   = __popc(NX - 1);
    const int bxl  = rest & (NX - 1);                 // logical N-tile
    const int byl  = ((rest >> lg) << 3) | xcd;       // logical M-panel, same-XCD grouped

    const int m0   = byl * 128;

    f32x4 acc[2][4];
#pragma unroll
    for (int a = 0; a < 2; a++)
#pragma unroll
        for (int b = 0; b < 4; b++) acc[a][b] = (f32x4){0.f, 0.f, 0.f, 0.f};

#define MG_FMA(A, W)                                                                        \
    _Pragma("unroll") for (int s = 0; s < 4; s++) {                                         \
        acc[0][s] = __builtin_amdgcn_mfma_f32_16x16x32_bf16(A[0], W[s],     acc[0][s], 0, 0, 0); \
        acc[0][s] = __builtin_amdgcn_mfma_f32_16x16x32_bf16(A[1], W[s],     acc[0][s], 0, 0, 0); \
        acc[0][s] = __builtin_amdgcn_mfma_f32_16x16x32_bf16(A[0], W[4 + s], acc[0][s], 0, 0, 0); \
        acc[1][s] = __builtin_amdgcn_mfma_f32_16x16x32_bf16(A[2], W[s],     acc[1][s], 0, 0, 0); \
        acc[1][s] = __builtin_amdgcn_mfma_f32_16x16x32_bf16(A[3], W[s],     acc[1][s], 0, 0, 0); \
        acc[1][s] = __builtin_amdgcn_mfma_f32_16x16x32_bf16(A[2], W[4 + s], acc[1][s], 0, 0, 0); }

    if constexpr (ASRC == 1) {
        // ---- fragment-tiled direct loads, 2-deep pipeline, no LDS/barriers.
        const int rt0 = (m0 + wave * 32) >> 4;                 // mt=0 16-row tile
        const unsigned short* pa_h = Ahg + (size_t)rt0 * KT * 512 + (lane << 3);
        const unsigned short* pa_l = Alg + (size_t)rt0 * KT * 512 + (lane << 3);
        const unsigned short* pw   = Wp + (size_t)bxl * KT * 4096 + (lane << 3);
        const size_t mto = (size_t)KT * 512;                   // next 16-row tile

#define MG_LDA(D, ktv) { const size_t _o = (size_t)(ktv) * 512;       \
        D[0] = *(const short8*)(pa_h + _o);                           \
        D[1] = *(const short8*)(pa_l + _o);                           \
        D[2] = *(const short8*)(pa_h + mto + _o);                     \
        D[3] = *(const short8*)(pa_l + mto + _o); }
#define MG_LDW(D, ktv) { const unsigned short* _p = pw + (size_t)(ktv) * 4096; \
        _Pragma("unroll") for (int s = 0; s < 4; s++) {               \
            D[s]     = *(const short8*)(_p + s * 1024);               \
            D[4 + s] = *(const short8*)(_p + s * 1024 + 512); } }

        short8 ca[4], cw[8], na[4], nw[8];
        MG_LDA(ca, 0)
        MG_LDW(cw, 0)
        for (int kt = 0; kt < KT; kt += 2) {      // KT is even for all users
            MG_LDA(na, kt + 1)
            MG_LDW(nw, kt + 1)
            MG_FMA(ca, cw)
            if (kt + 2 < KT) {
                MG_LDA(ca, kt + 2)
                MG_LDW(cw, kt + 2)
            }
            MG_FMA(na, nw)
        }
#undef MG_LDA
#undef MG_LDW
    } else {
        // ---- LDS-staged fp32->split conversion loop (ASRC 0 all kt; ASRC 2 kt<8)
        __shared__ unsigned short AhL[128 * 40];
        __shared__ unsigned short AlL[128 * 40];
        const int srow = tid >> 1, shalf = tid & 1;
        const int ktLds = (ASRC == 2) ? 8 : KT;

        for (int kt = 0; kt < ktLds; kt++) {
            {
                const int m  = m0 + srow;
                const int kb = kt * 32 + shalf * 16;
                const int lofs = srow * 40 + shalf * 16;
                const float* ap = (ASRC == 2) ? (Af + (size_t)(m >> 8) * 256 + kb)
                                              : (Af + (size_t)m * K + kb);
                float4 x0 = *(const float4*)(ap + 0);
                float4 x1 = *(const float4*)(ap + 4);
                float4 x2 = *(const float4*)(ap + 8);
                float4 x3 = *(const float4*)(ap + 12);
                float xv[16] = {x0.x, x0.y, x0.z, x0.w, x1.x, x1.y, x1.z, x1.w,
                                x2.x, x2.y, x2.z, x2.w, x3.x, x3.y, x3.z, x3.w};
                unsigned hw[8], lw[8];
#pragma unroll
                for (int q = 0; q < 8; q++) {
                    unsigned short h0 = f2bf(xv[2 * q]), h1 = f2bf(xv[2 * q + 1]);
                    unsigned short l0 = f2bf(xv[2 * q] - bf2f(h0));
                    unsigned short l1 = f2bf(xv[2 * q + 1] - bf2f(h1));
                    hw[q] = pk(h0, h1);
                    lw[q] = pk(l0, l1);
                }
                *(uint4*)&AhL[lofs]     = make_uint4(hw[0], hw[1], hw[2], hw[3]);
                *(uint4*)&AhL[lofs + 8] = make_uint4(hw[4], hw[5], hw[6], hw[7]);
                *(uint4*)&AlL[lofs]     = make_uint4(lw[0], lw[1], lw[2], lw[3]);
                *(uint4*)&AlL[lofs + 8] = make_uint4(lw[4], lw[5], lw[6], lw[7]);
            }
            __syncthreads();

            const unsigned short* wk = Wp + ((size_t)bxl * KT * 4 * 2 * 64 + lane) * 8
                                     + (size_t)kt * 4096;
            short8 wf[8];
#pragma unroll
            for (int s = 0; s < 4; s++) {
                wf[s]     = *(const short8*)(wk + (size_t)s * 1024);
                wf[4 + s] = *(const short8*)(wk + (size_t)s * 1024 + 512);
            }
            short8 af[4];
#pragma unroll
            for (int mt = 0; mt < 2; mt++) {
                const int r = wave * 32 + mt * 16 + l16;
                af[2 * mt]     = *(const short8*)&AhL[r * 40 + quad * 8];
                af[2 * mt + 1] = *(const short8*)&AlL[r * 40 + quad * 8];
            }
            MG_FMA(af, wf)
            __syncthreads();
        }

        if constexpr (ASRC == 2) {
            // ---- comb half: fragment-tiled direct loads (K-local = 128, KTc = 4)
            const int rt0 = (m0 + wave * 32) >> 4;
            const unsigned short* qah = Ahg + (size_t)rt0 * 4 * 512 + (lane << 3);
            const unsigned short* qal = Alg + (size_t)rt0 * 4 * 512 + (lane << 3);
            const size_t mto2 = 4 * 512;
            const unsigned short* pwb = Wp + ((size_t)bxl * KT * 4 * 2 * 64 + lane) * 8;
#pragma unroll 2
            for (int kt = 8; kt < KT; kt++) {
                const size_t o = (size_t)(kt - 8) * 512;
                short8 af[4], wf[8];
                af[0] = *(const short8*)(qah + o);
                af[1] = *(const short8*)(qal + o);
                af[2] = *(const short8*)(qah + mto2 + o);
                af[3] = *(const short8*)(qal + mto2 + o);
                const unsigned short* pk_ = pwb + (size_t)kt * 4096;
#pragma unroll
                for (int s = 0; s < 4; s++) {
                    wf[s]     = *(const short8*)(pk_ + s * 1024);
                    wf[4 + s] = *(const short8*)(pk_ + s * 1024 + 512);
                }
                MG_FMA(af, wf)
            }
        }
    }
#undef MG_FMA

    // ---- epilogue
    const int nbase = bxl * 64;
    const int KTn = N >> 5;
#pragma unroll
    for (int mt = 0; mt < 2; mt++) {
        const int mrow0 = m0 + wave * 32 + mt * 16 + quad * 4;
        float mk[4];
        if (MASK != 0) {
#pragma unroll
            for (int r = 0; r < 4; r++) mk[r] = maskf[mrow0 + r];
        }
#pragma unroll
        for (int s = 0; s < 4; s++) {
            const int n = nbase + s * 16 + l16;
            float bv;
            if (EPID == 1)
                bv = (n < 80) ? clsb[n] : (n < 84 ? regb[n - 80] : 0.f);
            else
                bv = bias[n];
#pragma unroll
            for (int r = 0; r < 4; r++) {
                const int m = mrow0 + r;
                float v = acc[mt][s][r] + bv;
                if (ACT) v = fmaxf(v, 0.f);
                bool st = true;
                if (MASK == 1) st = mk[r] > 0.5f;
                if (MASK == 2) st = mk[r] < 0.5f;
                if (st) {
                    if (OUTF & 1) Cf[(size_t)m * N + n] = v;
                    if (OUTF & 2) {
                        unsigned short hh = f2bf(v);
                        const size_t fa = fragaddr(m, n, KTn);
                        Ch[fa] = hh;
                        Cl[fa] = f2bf(v - bf2f(hh));
                    }
                    if (EPID == 1) {
                        if (n < 80)      o80[(size_t)m * 80 + n] = v;
                        else if (n < 84) o4[(size_t)m * 4 + (n - 80)] = v;
                    }
                }
            }
        }
    }
}

// ---------------- per-batch pooling of comb: mean & score-weighted
__global__ __launch_bounds__(128) void pool2_kernel(
    const float* __restrict__ comb, const float* __restrict__ scores,
    const float* __restrict__ wsum, float* __restrict__ meanp,
    float* __restrict__ attnp)
{
    int b = blockIdx.x, d = threadIdx.x;
    float ms = 0.f, as = 0.f;
    for (int n = 0; n < 256; n++) {
        float v = comb[((size_t)b * 256 + n) * 128 + d];
        ms += v;
        as = fmaf(scores[b * 256 + n], v, as);
    }
    meanp[b * 128 + d] = ms * (1.f / 256.f);
    attnp[b * 128 + d] = as / wsum[b];
}

// ---------------- aggregator
__global__ __launch_bounds__(256) void agg_kernel(
    const float* __restrict__ meanp, const float* __restrict__ attnp,
    const float* __restrict__ gw, const float* __restrict__ gb,
    float* __restrict__ g)
{
    int b = blockIdx.x, j = threadIdx.x;
    __shared__ float cat[256];
    cat[j] = (j < 128) ? meanp[b * 128 + j] : attnp[b * 128 + j - 128];
    __syncthreads();
    float acc = gb[j];
    for (int k = 0; k < 256; k++) acc = fmaf(cat[k], gw[k * 256 + j], acc);
    g[b * 256 + j] = acc > 0.f ? acc : 0.f;
}

// ---------------------------------------------------------------------------
extern "C" void kernel_launch(void* const* d_in, const int* in_sizes, int n_in,
                              void* d_out, int out_size, void* d_ws, size_t ws_size,
                              hipStream_t stream)
{
    (void)in_sizes; (void)n_in; (void)out_size;

    const float* images = (const float*)d_in[0];
    const float* patches = (const float*)d_in[1];
    const float* cw1 = (const float*)d_in[2];
    const float* cb1 = (const float*)d_in[3];
    const float* cw2 = (const float*)d_in[4];
    const float* cb2 = (const float*)d_in[5];
    const float* aw1 = (const float*)d_in[6];
    const float* ab1 = (const float*)d_in[7];
    const float* aw2 = (const float*)d_in[8];
    const float* ab2 = (const float*)d_in[9];
    const float* thr = (const float*)d_in[10];
    const float* bw1 = (const float*)d_in[11];
    const float* bb1 = (const float*)d_in[12];
    const float* bw2 = (const float*)d_in[13];
    const float* bb2 = (const float*)d_in[14];
    const float* bw3 = (const float*)d_in[15];
    const float* bb3 = (const float*)d_in[16];
    const float* bw4 = (const float*)d_in[17];
    const float* bb4 = (const float*)d_in[18];
    const float* sw1 = (const float*)d_in[19];
    const float* sb1 = (const float*)d_in[20];
    const float* sw2 = (const float*)d_in[21];
    const float* sb2 = (const float*)d_in[22];
    const float* gw  = (const float*)d_in[23];
    const float* gb  = (const float*)d_in[24];
    const float* dw1 = (const float*)d_in[25];
    const float* db1 = (const float*)d_in[26];
    const float* cls_w = (const float*)d_in[27];
    const float* cls_b = (const float*)d_in[28];
    const float* reg_w = (const float*)d_in[29];
    const float* reg_b = (const float*)d_in[30];
    float* out = (float*)d_out;
    float* o80 = out;
    float* o4  = out + 655360;

    // ---- workspace carve-up (bytes, 256-aligned)
    unsigned char* base = (unsigned char*)d_ws;
    size_t off = 0;
    auto alloc = [&](size_t bytes) -> unsigned char* {
        unsigned char* r = base + off;
        off += (bytes + 255) & ~(size_t)255;
        return r;
    };

    // fixed-size buffers first
    float*  scores = (float*)alloc(8192 * 4);
    float*  maskf  = (float*)alloc(8192 * 4);
    float*  wsumb  = (float*)alloc(32 * 4);
    float*  combf  = (float*)alloc((size_t)8192 * 128 * 4);
    float*  meanp  = (float*)alloc(4096 * 4);
    float*  attnp  = (float*)alloc(4096 * 4);
    float*  gbuf   = (float*)alloc(8192 * 4);
    float*  wtc2   = (float*)alloc((size_t)64 * 9 * 64 * 4);   // conv2 transposed weights

    typedef unsigned short ush;
    ush* wp_bw1 = (ush*)alloc((size_t)8 * 96 * 4096 * 2);
    ush* wp_bw2 = (ush*)alloc((size_t)8 * 16 * 4096 * 2);
    ush* wp_bw3 = (ush*)alloc((size_t)8 * 16 * 4096 * 2);
    ush* wp_bw4 = (ush*)alloc((size_t)2 * 16 * 4096 * 2);
    ush* wp_sw1 = (ush*)alloc((size_t)1 * 96 * 4096 * 2);
    ush* wp_sw2 = (ush*)alloc((size_t)2 * 2 * 4096 * 2);
    ush* wp_dw1 = (ush*)alloc((size_t)4 * 12 * 4096 * 2);
    ush* wp_det = (ush*)alloc((size_t)2 * 8 * 4096 * 2);

    ush* hb1h = (ush*)alloc((size_t)8192 * 512 * 2);
    ush* hb1l = (ush*)alloc((size_t)8192 * 512 * 2);
    ush* hb2h = (ush*)alloc((size_t)8192 * 512 * 2);
    ush* hb2l = (ush*)alloc((size_t)8192 * 512 * 2);
    ush* hb3h = (ush*)alloc((size_t)8192 * 512 * 2);
    ush* hb3l = (ush*)alloc((size_t)8192 * 512 * 2);
    ush* hsh  = (ush*)alloc((size_t)8192 * 64 * 2);
    ush* hsl  = (ush*)alloc((size_t)8192 * 64 * 2);
    ush* combh = (ush*)alloc((size_t)8192 * 128 * 2);
    ush* combl = (ush*)alloc((size_t)8192 * 128 * 2);
    ush* hdh  = (ush*)alloc((size_t)8192 * 256 * 2);
    ush* hdl  = (ush*)alloc((size_t)8192 * 256 * 2);

    // slice-sized buffers: x1 + tokd
    size_t remain = (ws_size > off) ? (ws_size - off) : 0;
    int SL = 8;
    while (SL > 1) {
        size_t need = (size_t)SL * 64 * 256 * 256 * 4 + (size_t)SL * 64 * 128 * 16 * 8 + 1024;
        if (need <= remain) break;
        SL >>= 1;
    }
    float*  x1   = (float*)alloc((size_t)SL * 64 * 256 * 256 * 4);
    double* tokd = (double*)alloc((size_t)SL * 64 * 128 * 16 * 8);

    // patches split buffers (fragment-tiled): alias the dead x1 region when big
    // enough (SL=8: 134MB >= 100.7MB), else dedicated alloc, else fall back.
    const size_t ps_bytes = (size_t)8192 * 3072 * 2;   // 50.33 MB per plane
    ush* psh = nullptr;
    ush* psl = nullptr;
    int have_split = 0;
    if ((size_t)SL * 64 * 256 * 256 * 4 >= 2 * ps_bytes) {
        psh = (ush*)x1;
        psl = (ush*)((unsigned char*)x1 + ps_bytes);
        have_split = 1;
    } else {
        size_t rem2 = (ws_size > off) ? (ws_size - off) : 0;
        if (rem2 >= 2 * ps_bytes + 1024) {
            psh = (ush*)alloc(ps_bytes);
            psl = (ush*)alloc(ps_bytes);
            have_split = 1;
        }
    }

    // ---- weight preps
    {
        wprep_conv2<<<(64 * 9 * 64 + 255) / 256, 256, 0, stream>>>(cw2, wtc2);
        int t1 = 8 * 96 * 4 * 64;  wprep<<<(t1 + 255) / 256, 256, 0, stream>>>(bw1, wp_bw1, 3072, 512, 512);
        int t2 = 8 * 16 * 4 * 64;  wprep<<<(t2 + 255) / 256, 256, 0, stream>>>(bw2, wp_bw2, 512, 512, 512);
                                   wprep<<<(t2 + 255) / 256, 256, 0, stream>>>(bw3, wp_bw3, 512, 512, 512);
        int t4 = 2 * 16 * 4 * 64;  wprep<<<(t4 + 255) / 256, 256, 0, stream>>>(bw4, wp_bw4, 512, 128, 128);
        int t5 = 1 * 96 * 4 * 64;  wprep<<<(t5 + 255) / 256, 256, 0, stream>>>(sw1, wp_sw1, 3072, 64, 64);
        int t6 = 2 * 2 * 4 * 64;   wprep<<<(t6 + 255) / 256, 256, 0, stream>>>(sw2, wp_sw2, 64, 128, 128);
        int t7 = 4 * 12 * 4 * 64;  wprep<<<(t7 + 255) / 256, 256, 0, stream>>>(dw1, wp_dw1, 384, 256, 256);
        int t8 = 2 * 8 * 4 * 64;   wprep_det<<<(t8 + 255) / 256, 256, 0, stream>>>(cls_w, reg_w, wp_det);
    }

    // ---- backbone + attention scores, batch-sliced
    for (int s = 0; s < B_ALL / SL; s++) {
        conv1_kernel<<<dim3(256, SL), 256, 0, stream>>>(images, cw1, cb1, x1, s * SL);
        conv2_kernel<<<dim3(128, SL), 256, 0, stream>>>(x1, wtc2, cb2, tokd);
        attn_kernel<<<dim3(256, SL), 64, 0, stream>>>(tokd, aw1, ab1, aw2, ab2,
                                                      thr, scores, maskf, s * SL);
    }
    wsum_kernel<<<32, 256, 0, stream>>>(scores, wsumb);

    // ---- experts (split-bf16 MFMA)
    if (have_split) {
        asplit_kernel<<<(8192 * 3072) / (8 * 256), 256, 0, stream>>>(patches, psh, psl);
        mgemm<1, 1, 0, 2, 0><<<dim3(8, 64), 256, 0, stream>>>(
            nullptr, psh, psl, wp_bw1, bb1, nullptr, hb1h, hb1l, nullptr,
            3072, 512, 96, nullptr, nullptr, nullptr, nullptr);
        mgemm<1, 1, 0, 2, 0><<<dim3(1, 64), 256, 0, stream>>>(
            nullptr, psh, psl, wp_sw1, sb1, nullptr, hsh, hsl, nullptr,
            3072, 64, 96, nullptr, nullptr, nullptr, nullptr);
    } else {
        mgemm<0, 1, 0, 2, 0><<<dim3(8, 64), 256, 0, stream>>>(
            patches, nullptr, nullptr, wp_bw1, bb1, nullptr, hb1h, hb1l, nullptr,
            3072, 512, 96, nullptr, nullptr, nullptr, nullptr);
        mgemm<0, 1, 0, 2, 0><<<dim3(1, 64), 256, 0, stream>>>(
            patches, nullptr, nullptr, wp_sw1, sb1, nullptr, hsh, hsl, nullptr,
            3072, 64, 96, nullptr, nullptr, nullptr, nullptr);
    }
    mgemm<1, 1, 0, 2, 0><<<dim3(8, 64), 256, 0, stream>>>(
        nullptr, hb1h, hb1l, wp_bw2, bb2, nullptr, hb2h, hb2l, nullptr,
        512, 512, 16, nullptr, nullptr, nullptr, nullptr);
    mgemm<1, 1, 0, 2, 0><<<dim3(8, 64), 256, 0, stream>>>(
        nullptr, hb2h, hb2l, wp_bw3, bb3, nullptr, hb3h, hb3l, nullptr,
        512, 512, 16, nullptr, nullptr, nullptr, nullptr);
    mgemm<1, 0, 1, 3, 0><<<dim3(2, 64), 256, 0, stream>>>(
        nullptr, hb3h, hb3l, wp_bw4, bb4, combf, combh, combl, maskf,
        512, 128, 16, nullptr, nullptr, nullptr, nullptr);
    mgemm<1, 0, 2, 3, 0><<<dim3(2, 64), 256, 0, stream>>>(
        nullptr, hsh, hsl, wp_sw2, sb2, combf, combh, combl, maskf,
        64, 128, 2, nullptr, nullptr, nullptr, nullptr);

    // ---- aggregate + detection
    pool2_kernel<<<32, 128, 0, stream>>>(combf, scores, wsumb, meanp, attnp);
    agg_kernel<<<32, 256, 0, stream>>>(meanp, attnp, gw, gb, gbuf);
    mgemm<2, 1, 0, 2, 0><<<dim3(4, 64), 256, 0, stream>>>(
        gbuf, combh, combl, wp_dw1, db1, nullptr, hdh, hdl, nullptr,
        384, 256, 12, nullptr, nullptr, nullptr, nullptr);
    mgemm<1, 0, 0, 0, 1><<<dim3(2, 64), 256, 0, stream>>>(
        nullptr, hdh, hdl, wp_det, nullptr, nullptr, nullptr, nullptr, nullptr,
        256, 128, 8, o80, o4, cls_b, reg_b);
}

// Round 4
// 1255.417 us; speedup vs baseline: 1.1308x; 1.0796x over previous
//
#include <hip/hip_runtime.h>
#include <math.h>

// ---------------------------------------------------------------------------
// AttentionRoutingDetector — R9: W deduplicated through LDS in the ASRC=1
// GEMM path. R8 analysis: kernel sat at the ~28 B/cy/CU VMEM ceiling with
// 96 KB/kt/CU issued, of which W was 4x redundant (all 4 waves load the same
// 8 KB fragment slice). Now W is staged once per block per kt via
// global_load_lds (W is already fragment-contiguous -> linear LDS dest ok),
// double-buffered, one __syncthreads per kt (conservative drain; 2 blocks/CU
// cover the stall). A remains direct coalesced fragment loads prefetched one
// kt ahead. Per-CU VMEM 96->48 KB/kt. W bytes via LDS are bit-identical and
// MFMA order unchanged -> numerics bit-identical to R5..R8.
// ---------------------------------------------------------------------------

#define B_ALL 32

typedef __attribute__((ext_vector_type(8))) short short8;
typedef __attribute__((ext_vector_type(4))) float f32x4;

__device__ __forceinline__ unsigned short f2bf(float x) {
    unsigned u = __float_as_uint(x);
    return (unsigned short)((u + 0x7FFFu + ((u >> 16) & 1u)) >> 16);
}
__device__ __forceinline__ float bf2f(unsigned short h) {
    return __uint_as_float(((unsigned)h) << 16);
}
__device__ __forceinline__ unsigned pk(unsigned short a, unsigned short b) {
    return (unsigned)a | ((unsigned)b << 16);
}

// fragment-tiled address for split A/C planes: element (m, k) of a matrix
// whose K-dim tile count is KTn (= K/32). Lane-contiguous per (16-row,32-k) tile.
__device__ __forceinline__ size_t fragaddr(int m, int n, int KTn) {
    return ((size_t)((m >> 4) * KTn + (n >> 5)) * 4 + ((n & 31) >> 3)) * 128
           + (size_t)(m & 15) * 8 + (n & 7);
}

// ---------------- conv1: (b,3,512,512) -> relu -> (b,64,256,256), stride 2
__global__ __launch_bounds__(256) void conv1_kernel(
    const float* __restrict__ img, const float* __restrict__ w,
    const float* __restrict__ bias, float* __restrict__ x1, int b0)
{
    const int ow = threadIdx.x;
    const int oh = blockIdx.x;
    const int bl = blockIdx.y;
    const int b  = b0 + bl;

    const float* ib = img + (size_t)b * 3 * 512 * 512;
    float in[3][3][3];
#pragma unroll
    for (int c = 0; c < 3; c++)
#pragma unroll
        for (int kh = 0; kh < 3; kh++) {
            int ih = oh * 2 + kh;
#pragma unroll
            for (int kw = 0; kw < 3; kw++) {
                int iw = ow * 2 + kw;
                in[c][kh][kw] = (ih < 512 && iw < 512)
                    ? ib[((size_t)c * 512 + ih) * 512 + iw] : 0.f;
            }
        }

    float* ob = x1 + ((size_t)bl * 64 * 256 + oh) * 256 + ow;
#pragma unroll 2
    for (int oc = 0; oc < 64; oc++) {
        const float* wp = w + oc * 27;
        float p[3] = {0.f, 0.f, 0.f};
#pragma unroll
        for (int c = 0; c < 3; c++)
#pragma unroll
            for (int kh = 0; kh < 3; kh++)
#pragma unroll
                for (int kw = 0; kw < 3; kw++)
                    p[c] = fmaf(in[c][kh][kw], wp[(c * 3 + kh) * 3 + kw], p[c]);
        double s = (double)bias[oc] + ((double)p[0] + (double)p[1] + (double)p[2]);
        float r = (float)s;
        ob[(size_t)oc * 256 * 256] = r > 0.f ? r : 0.f;
    }
}

// ---------------- conv2 weight transpose: w[oc][ic][kh][kw] -> wt[ic][kh][kw][oc]
__global__ __launch_bounds__(256) void wprep_conv2(
    const float* __restrict__ w, float* __restrict__ wt)
{
    int idx = blockIdx.x * 256 + threadIdx.x;
    if (idx >= 64 * 9 * 64) return;
    int oc = idx & 63;
    int r  = idx >> 6;          // ic*9 + kh*3 + kw
    wt[r * 64 + oc] = w[(size_t)oc * 576 + r];
}

// ---------------- conv2 + fused 8x8 pool partials (no LDS, no barriers).
__global__ __launch_bounds__(256, 3) void conv2_kernel(
    const float* __restrict__ x1, const float* __restrict__ wt,
    const float* __restrict__ bias, double* __restrict__ tokd)
{
    const int tid  = threadIdx.x;
    const int lane = tid & 63;
    const int wave = __builtin_amdgcn_readfirstlane(tid >> 6);   // 0..3, scalar
    const int oh   = blockIdx.x;          // 0..127
    const int bl   = blockIdx.y;
    const int ow0  = lane * 2;            // this thread: ow0, ow0+1

    const float* xb = x1 + (size_t)bl * 64 * 256 * 256;

    float  acc[2][16];
    double accd[2][16];
#pragma unroll
    for (int j = 0; j < 2; j++)
#pragma unroll
        for (int o = 0; o < 16; o++) { acc[j][o] = 0.f; accd[j][o] = 0.0; }

    for (int ic0 = 0; ic0 < 64; ic0 += 8) {
#pragma unroll 2
        for (int ic = 0; ic < 8; ic++) {
            const int icg = ic0 + ic;
#pragma unroll
            for (int kh = 0; kh < 3; kh++) {
                const int ih = oh * 2 + kh;
                if (ih < 256) {
                    const float* rp = xb + ((size_t)icg * 256 + ih) * 256 + ow0 * 2;
                    float4 f4 = *(const float4*)rp;            // cols 4L..4L+3
                    float  f5 = (ow0 < 126) ? rp[4] : 0.f;     // col 4L+4 (lane63 OOB=0)
                    float iv[3][2] = {{f4.x, f4.z}, {f4.y, f4.w}, {f4.z, f5}};
                    const float* wrow = wt + (size_t)((icg * 3 + kh) * 3) * 64 + wave * 16;
#pragma unroll
                    for (int kw = 0; kw < 3; kw++) {
                        const float* wp = wrow + kw * 64;       // uniform -> s_load
#pragma unroll
                        for (int o = 0; o < 16; o++) {
                            float wv = wp[o];
                            acc[0][o] = fmaf(iv[kw][0], wv, acc[0][o]);
                            acc[1][o] = fmaf(iv[kw][1], wv, acc[1][o]);
                        }
                    }
                }
            }
        }
        // carry this 72-term fp32 partial into fp64 (same cadence as R4)
#pragma unroll
        for (int j = 0; j < 2; j++)
#pragma unroll
            for (int o = 0; o < 16; o++) {
                accd[j][o] += (double)acc[j][o];
                acc[j][o] = 0.f;
            }
    }

    // bias + relu (fp32-rounded) then pool partial: sum 8 consecutive ow.
#pragma unroll
    for (int o = 0; o < 16; o++) {
        const int oc = wave * 16 + o;
        const double bv = (double)bias[oc];
        double s = (double)fmaxf((float)(accd[0][o] + bv), 0.f)
                 + (double)fmaxf((float)(accd[1][o] + bv), 0.f);
        s += __shfl_xor(s, 1);
        s += __shfl_xor(s, 2);
        if ((lane & 3) == 0)
            tokd[(((size_t)bl * 64 + oc) * 128 + oh) * 16 + (lane >> 2)] = s;
    }
}

// ---------------- attention MLP from pooled tokens (fp64) + fp32-emulated
// sigmoid chain (identical to R3's verified decision rule).
__global__ __launch_bounds__(64) void attn_kernel(
    const double* __restrict__ tokd, const float* __restrict__ aw1,
    const float* __restrict__ ab1, const float* __restrict__ aw2,
    const float* __restrict__ ab2, const float* __restrict__ thrp,
    float* __restrict__ scores, float* __restrict__ maskf, int b0)
{
    const int c  = threadIdx.x;
    const int n  = blockIdx.x;
    const int bl = blockIdx.y;
    const int i = n >> 4, j = n & 15;

    const double* tp = tokd + (((size_t)bl * 64 + c) * 128 + i * 8) * 16 + j;
    double s = 0.0;
#pragma unroll
    for (int p = 0; p < 8; p++) s += tp[p * 16];

    __shared__ double tok[64];
    __shared__ double h[32];
    tok[c] = s * (1.0 / 64.0);
    __syncthreads();
    if (c < 32) {
        double acc = (double)ab1[c];
        for (int k = 0; k < 64; k++) acc += tok[k] * (double)aw1[k * 32 + c];
        h[c] = acc > 0.0 ? acc : 0.0;
    }
    __syncthreads();
    if (c == 0) {
        double logit = (double)ab2[0];
        for (int k = 0; k < 32; k++) logit += h[k] * (double)aw2[k];
        float lf = (float)logit;
        float e1 = (float)exp(-(double)lf);
        float d1 = 1.0f + e1;
        float sc = (float)(1.0 / (double)d1);
        float t  = sc - thrp[0];
        float e2 = (float)exp(-(double)t);
        float d2 = 1.0f + e2;
        float soft = (float)(1.0 / (double)d2);
        scores[(size_t)(b0 + bl) * 256 + n] = sc;
        maskf[(size_t)(b0 + bl) * 256 + n] = (soft > 0.5f) ? 1.f : 0.f;
    }
}

// ---------------- per-batch score sum
__global__ __launch_bounds__(256) void wsum_kernel(
    const float* __restrict__ scores, float* __restrict__ wsum)
{
    int b = blockIdx.x, t = threadIdx.x;
    float v = scores[b * 256 + t];
#pragma unroll
    for (int o = 32; o > 0; o >>= 1) v += __shfl_down(v, o);
    __shared__ float ls[4];
    if ((t & 63) == 0) ls[t >> 6] = v;
    __syncthreads();
    if (t == 0) wsum[b] = (ls[0] + ls[1] + ls[2] + ls[3]) + 1e-6f;
}

// ---------------- patches -> split bf16 hi/lo planes, FRAGMENT-TILED.
__global__ __launch_bounds__(256) void asplit_kernel(
    const float* __restrict__ A, unsigned short* __restrict__ Ah,
    unsigned short* __restrict__ Al)
{
    const size_t g = (size_t)blockIdx.x * 256 + threadIdx.x;
    const int tile = (int)(g >> 6);
    const int l    = (int)(g & 63);
    const int rt = tile / 96, kt = tile % 96;
    const int m  = rt * 16 + (l & 15);
    const int k0 = kt * 32 + (l >> 4) * 8;

    const float* ap = A + (size_t)m * 3072 + k0;
    float4 x0 = *(const float4*)(ap);
    float4 x1 = *(const float4*)(ap + 4);
    float xv[8] = {x0.x, x0.y, x0.z, x0.w, x1.x, x1.y, x1.z, x1.w};
    unsigned hw[4], lw[4];
#pragma unroll
    for (int q = 0; q < 4; q++) {
        unsigned short h0 = f2bf(xv[2 * q]), h1 = f2bf(xv[2 * q + 1]);
        hw[q] = pk(h0, h1);
        lw[q] = pk(f2bf(xv[2 * q] - bf2f(h0)), f2bf(xv[2 * q + 1] - bf2f(h1)));
    }
    *(uint4*)(Ah + g * 8) = make_uint4(hw[0], hw[1], hw[2], hw[3]);
    *(uint4*)(Al + g * 8) = make_uint4(lw[0], lw[1], lw[2], lw[3]);
}

// ---------------- weight prep: pack W (KxN fp32) into MFMA fragment layout,
// split bf16 hi/lo: Wp[nt][kt][sub][h][lane][8]
__global__ __launch_bounds__(256) void wprep(
    const float* __restrict__ W, unsigned short* __restrict__ Wp, int K, int N, int Npad)
{
    int idx = blockIdx.x * 256 + threadIdx.x;
    int KT = K >> 5;
    int total = (Npad >> 6) * KT * 4 * 64;
    if (idx >= total) return;
    int lane = idx & 63;
    int sub  = (idx >> 6) & 3;
    int t    = idx >> 8;
    int kt = t % KT, nt = t / KT;
    int n  = nt * 64 + sub * 16 + (lane & 15);
    int k0 = kt * 32 + (lane >> 4) * 8;
    unsigned hw[4], lw[4];
#pragma unroll
    for (int q = 0; q < 4; q++) {
        float x0 = (n < N) ? W[(size_t)(k0 + 2 * q) * N + n] : 0.f;
        float x1 = (n < N) ? W[(size_t)(k0 + 2 * q + 1) * N + n] : 0.f;
        unsigned short h0 = f2bf(x0), h1 = f2bf(x1);
        hw[q] = pk(h0, h1);
        lw[q] = pk(f2bf(x0 - bf2f(h0)), f2bf(x1 - bf2f(h1)));
    }
    size_t base = ((((size_t)(nt * KT + kt) * 4 + sub) * 2) * 64 + lane) * 8;
    *(uint4*)(Wp + base)       = make_uint4(hw[0], hw[1], hw[2], hw[3]);
    *(uint4*)(Wp + base + 512) = make_uint4(lw[0], lw[1], lw[2], lw[3]);
}

// det head weights: concat cls_w (256x80) | reg_w (256x4), pad to 128 cols
__global__ __launch_bounds__(256) void wprep_det(
    const float* __restrict__ Wc, const float* __restrict__ Wr,
    unsigned short* __restrict__ Wp)
{
    int idx = blockIdx.x * 256 + threadIdx.x;
    const int KT = 8;
    int total = 2 * KT * 4 * 64;
    if (idx >= total) return;
    int lane = idx & 63;
    int sub  = (idx >> 6) & 3;
    int t    = idx >> 8;
    int kt = t % KT, nt = t / KT;
    int n  = nt * 64 + sub * 16 + (lane & 15);
    int k0 = kt * 32 + (lane >> 4) * 8;
    unsigned hw[4], lw[4];
#pragma unroll
    for (int q = 0; q < 4; q++) {
        int ka = k0 + 2 * q, kb = k0 + 2 * q + 1;
        float x0 = (n < 80) ? Wc[(size_t)ka * 80 + n] : (n < 84 ? Wr[(size_t)ka * 4 + n - 80] : 0.f);
        float x1 = (n < 80) ? Wc[(size_t)kb * 80 + n] : (n < 84 ? Wr[(size_t)kb * 4 + n - 80] : 0.f);
        unsigned short h0 = f2bf(x0), h1 = f2bf(x1);
        hw[q] = pk(h0, h1);
        lw[q] = pk(f2bf(x0 - bf2f(h0)), f2bf(x1 - bf2f(h1)));
    }
    size_t base = ((((size_t)(nt * KT + kt) * 4 + sub) * 2) * 64 + lane) * 8;
    *(uint4*)(Wp + base)       = make_uint4(hw[0], hw[1], hw[2], hw[3]);
    *(uint4*)(Wp + base + 512) = make_uint4(lw[0], lw[1], lw[2], lw[3]);
}

// ---------------- split-bf16 MFMA GEMM: C = epi(A @ W + bias)
// Tile 128(M) x 64(N) x 32(K); 4 waves, each 32 rows x 64 cols (8 C-tiles).
// ASRC: 0 = fp32 A row-major (convert in LDS staging);
//       1 = pre-split A fragment-tiled, direct coalesced A loads prefetched
//           one kt ahead; W staged ONCE per block per kt into double-buffered
//           LDS via global_load_lds (removes the 4x per-wave W redundancy);
//       2 = concat: kt<8 -> g fp32 via LDS (row m>>8, width 256);
//           kt>=8 -> comb split fragment-tiled, direct loads.
// ACT: 1 = relu. MASK: 0 none / 1 keep(mask==1) / 2 keep(mask==0).
// OUTF: bit0 fp32 C row-major, bit1 split Ch/Cl FRAGMENT-TILED (KTn = N/32).
// EPID: 1 = detection dual-store. XCD swizzle (R6) retained.
template <int ASRC, int ACT, int MASK, int OUTF, int EPID>
__global__ __launch_bounds__(256, 2) void mgemm(
    const float* __restrict__ Af, const unsigned short* __restrict__ Ahg,
    const unsigned short* __restrict__ Alg, const unsigned short* __restrict__ Wp,
    const float* __restrict__ bias, float* __restrict__ Cf,
    unsigned short* __restrict__ Ch, unsigned short* __restrict__ Cl,
    const float* __restrict__ maskf, int K, int N, int KT,
    float* __restrict__ o80, float* __restrict__ o4,
    const float* __restrict__ clsb, const float* __restrict__ regb)
{
    const int tid  = threadIdx.x;
    const int wave = tid >> 6, lane = tid & 63;
    const int quad = lane >> 4, l16 = lane & 15;

    // ---- bijective XCD swizzle (grid is (NX, 64), NX in {1,2,4,8}) ----
    const int NX   = gridDim.x;
    const int lb   = blockIdx.y * NX + blockIdx.x;   // HW dispatch order, x fastest
    const int xcd  = lb & 7;                          // lands on this XCD (mod-8 RR)
    const int rest = lb >> 3;
    const int lg   = __popc(NX - 1);
    const int bxl  = rest & (NX - 1);                 // logical N-tile
    const int byl  = ((rest >> lg) << 3) | xcd;       // logical M-panel, same-XCD grouped

    const int m0   = byl * 128;

    f32x4 acc[2][4];
#pragma unroll
    for (int a = 0; a < 2; a++)
#pragma unroll
        for (int b = 0; b < 4; b++) acc[a][b] = (f32x4){0.f, 0.f, 0.f, 0.f};

#define MG_FMA(A, W)                                                                        \
    _Pragma("unroll") for (int s = 0; s < 4; s++) {                                         \
        acc[0][s] = __builtin_amdgcn_mfma_f32_16x16x32_bf16(A[0], W[s],     acc[0][s], 0, 0, 0); \
        acc[0][s] = __builtin_amdgcn_mfma_f32_16x16x32_bf16(A[1], W[s],     acc[0][s], 0, 0, 0); \
        acc[0][s] = __builtin_amdgcn_mfma_f32_16x16x32_bf16(A[0], W[4 + s], acc[0][s], 0, 0, 0); \
        acc[1][s] = __builtin_amdgcn_mfma_f32_16x16x32_bf16(A[2], W[s],     acc[1][s], 0, 0, 0); \
        acc[1][s] = __builtin_amdgcn_mfma_f32_16x16x32_bf16(A[3], W[s],     acc[1][s], 0, 0, 0); \
        acc[1][s] = __builtin_amdgcn_mfma_f32_16x16x32_bf16(A[2], W[4 + s], acc[1][s], 0, 0, 0); }

    if constexpr (ASRC == 1) {
        // ---- A: direct fragment loads; W: LDS double-buffer, staged once/block.
        __shared__ unsigned short WL[2][4096];          // 8KB per kt-slice
        const int rt0 = (m0 + wave * 32) >> 4;
        const unsigned short* pa_h = Ahg + (size_t)rt0 * KT * 512 + (lane << 3);
        const unsigned short* pa_l = Alg + (size_t)rt0 * KT * 512 + (lane << 3);
        const size_t mto = (size_t)KT * 512;
        // staging source: wave w covers 1024 shorts (2 wave-ops x 512)
        const unsigned short* wsrc = Wp + (size_t)bxl * KT * 4096
                                   + (size_t)wave * 1024 + ((size_t)lane << 3);
        unsigned short* wd0 = &WL[0][wave * 1024];      // wave-uniform LDS bases
        unsigned short* wd1 = &WL[1][wave * 1024];

#define MG_STW(dst, ktv) do {                                                         \
        const unsigned short* _g = wsrc + (size_t)(ktv) * 4096;                       \
        __builtin_amdgcn_global_load_lds(                                             \
            (const __attribute__((address_space(1))) void*)_g,                        \
            (__attribute__((address_space(3))) void*)(dst), 16, 0, 0);                \
        __builtin_amdgcn_global_load_lds(                                             \
            (const __attribute__((address_space(1))) void*)(_g + 512),                \
            (__attribute__((address_space(3))) void*)((dst) + 512), 16, 0, 0);        \
    } while (0)

#define MG_LDA(D, ktv) { const size_t _o = (size_t)(ktv) * 512;       \
        D[0] = *(const short8*)(pa_h + _o);                           \
        D[1] = *(const short8*)(pa_l + _o);                           \
        D[2] = *(const short8*)(pa_h + mto + _o);                     \
        D[3] = *(const short8*)(pa_l + mto + _o); }
#define MG_LDW(D, buf) _Pragma("unroll") for (int s = 0; s < 4; s++) {    \
        D[s]     = *(const short8*)&WL[buf][(s * 2) * 512 + (lane << 3)];     \
        D[4 + s] = *(const short8*)&WL[buf][(s * 2 + 1) * 512 + (lane << 3)]; }

        short8 ca[4], na[4];
        MG_STW(wd0, 0);
        MG_LDA(ca, 0)
        for (int kt = 0; kt < KT; kt += 2) {      // KT even for all users
            __syncthreads();                       // stage(kt)+A(kt) drained; buf1 reads done
            if (kt + 1 < KT) { MG_STW(wd1, kt + 1); MG_LDA(na, kt + 1) }
            {
                short8 w0[8];
                MG_LDW(w0, 0)
                MG_FMA(ca, w0)
            }
            __syncthreads();                       // stage(kt+1)+A(kt+1) drained; buf0 reads done
            if (kt + 2 < KT) { MG_STW(wd0, kt + 2); MG_LDA(ca, kt + 2) }
            {
                short8 w1[8];
                MG_LDW(w1, 1)
                MG_FMA(na, w1)
            }
        }
#undef MG_STW
#undef MG_LDA
#undef MG_LDW
    } else {
        // ---- LDS-staged fp32->split conversion loop (ASRC 0 all kt; ASRC 2 kt<8)
        __shared__ unsigned short AhL[128 * 40];
        __shared__ unsigned short AlL[128 * 40];
        const int srow = tid >> 1, shalf = tid & 1;
        const int ktLds = (ASRC == 2) ? 8 : KT;

        for (int kt = 0; kt < ktLds; kt++) {
            {
                const int m  = m0 + srow;
                const int kb = kt * 32 + shalf * 16;
                const int lofs = srow * 40 + shalf * 16;
                const float* ap = (ASRC == 2) ? (Af + (size_t)(m >> 8) * 256 + kb)
                                              : (Af + (size_t)m * K + kb);
                float4 x0 = *(const float4*)(ap + 0);
                float4 x1 = *(const float4*)(ap + 4);
                float4 x2 = *(const float4*)(ap + 8);
                float4 x3 = *(const float4*)(ap + 12);
                float xv[16] = {x0.x, x0.y, x0.z, x0.w, x1.x, x1.y, x1.z, x1.w,
                                x2.x, x2.y, x2.z, x2.w, x3.x, x3.y, x3.z, x3.w};
                unsigned hw[8], lw[8];
#pragma unroll
                for (int q = 0; q < 8; q++) {
                    unsigned short h0 = f2bf(xv[2 * q]), h1 = f2bf(xv[2 * q + 1]);
                    unsigned short l0 = f2bf(xv[2 * q] - bf2f(h0));
                    unsigned short l1 = f2bf(xv[2 * q + 1] - bf2f(h1));
                    hw[q] = pk(h0, h1);
                    lw[q] = pk(l0, l1);
                }
                *(uint4*)&AhL[lofs]     = make_uint4(hw[0], hw[1], hw[2], hw[3]);
                *(uint4*)&AhL[lofs + 8] = make_uint4(hw[4], hw[5], hw[6], hw[7]);
                *(uint4*)&AlL[lofs]     = make_uint4(lw[0], lw[1], lw[2], lw[3]);
                *(uint4*)&AlL[lofs + 8] = make_uint4(lw[4], lw[5], lw[6], lw[7]);
            }
            __syncthreads();

            const unsigned short* wk = Wp + ((size_t)bxl * KT * 4 * 2 * 64 + lane) * 8
                                     + (size_t)kt * 4096;
            short8 wf[8];
#pragma unroll
            for (int s = 0; s < 4; s++) {
                wf[s]     = *(const short8*)(wk + (size_t)s * 1024);
                wf[4 + s] = *(const short8*)(wk + (size_t)s * 1024 + 512);
            }
            short8 af[4];
#pragma unroll
            for (int mt = 0; mt < 2; mt++) {
                const int r = wave * 32 + mt * 16 + l16;
                af[2 * mt]     = *(const short8*)&AhL[r * 40 + quad * 8];
                af[2 * mt + 1] = *(const short8*)&AlL[r * 40 + quad * 8];
            }
            MG_FMA(af, wf)
            __syncthreads();
        }

        if constexpr (ASRC == 2) {
            // ---- comb half: fragment-tiled direct loads (K-local = 128, KTc = 4)
            const int rt0 = (m0 + wave * 32) >> 4;
            const unsigned short* qah = Ahg + (size_t)rt0 * 4 * 512 + (lane << 3);
            const unsigned short* qal = Alg + (size_t)rt0 * 4 * 512 + (lane << 3);
            const size_t mto2 = 4 * 512;
            const unsigned short* pwb = Wp + ((size_t)bxl * KT * 4 * 2 * 64 + lane) * 8;
#pragma unroll 2
            for (int kt = 8; kt < KT; kt++) {
                const size_t o = (size_t)(kt - 8) * 512;
                short8 af[4], wf[8];
                af[0] = *(const short8*)(qah + o);
                af[1] = *(const short8*)(qal + o);
                af[2] = *(const short8*)(qah + mto2 + o);
                af[3] = *(const short8*)(qal + mto2 + o);
                const unsigned short* pk_ = pwb + (size_t)kt * 4096;
#pragma unroll
                for (int s = 0; s < 4; s++) {
                    wf[s]     = *(const short8*)(pk_ + s * 1024);
                    wf[4 + s] = *(const short8*)(pk_ + s * 1024 + 512);
                }
                MG_FMA(af, wf)
            }
        }
    }
#undef MG_FMA

    // ---- epilogue
    const int nbase = bxl * 64;
    const int KTn = N >> 5;
#pragma unroll
    for (int mt = 0; mt < 2; mt++) {
        const int mrow0 = m0 + wave * 32 + mt * 16 + quad * 4;
        float mk[4];
        if (MASK != 0) {
#pragma unroll
            for (int r = 0; r < 4; r++) mk[r] = maskf[mrow0 + r];
        }
#pragma unroll
        for (int s = 0; s < 4; s++) {
            const int n = nbase + s * 16 + l16;
            float bv;
            if (EPID == 1)
                bv = (n < 80) ? clsb[n] : (n < 84 ? regb[n - 80] : 0.f);
            else
                bv = bias[n];
#pragma unroll
            for (int r = 0; r < 4; r++) {
                const int m = mrow0 + r;
                float v = acc[mt][s][r] + bv;
                if (ACT) v = fmaxf(v, 0.f);
                bool st = true;
                if (MASK == 1) st = mk[r] > 0.5f;
                if (MASK == 2) st = mk[r] < 0.5f;
                if (st) {
                    if (OUTF & 1) Cf[(size_t)m * N + n] = v;
                    if (OUTF & 2) {
                        unsigned short hh = f2bf(v);
                        const size_t fa = fragaddr(m, n, KTn);
                        Ch[fa] = hh;
                        Cl[fa] = f2bf(v - bf2f(hh));
                    }
                    if (EPID == 1) {
                        if (n < 80)      o80[(size_t)m * 80 + n] = v;
                        else if (n < 84) o4[(size_t)m * 4 + (n - 80)] = v;
                    }
                }
            }
        }
    }
}

// ---------------- per-batch pooling of comb: mean & score-weighted
__global__ __launch_bounds__(128) void pool2_kernel(
    const float* __restrict__ comb, const float* __restrict__ scores,
    const float* __restrict__ wsum, float* __restrict__ meanp,
    float* __restrict__ attnp)
{
    int b = blockIdx.x, d = threadIdx.x;
    float ms = 0.f, as = 0.f;
    for (int n = 0; n < 256; n++) {
        float v = comb[((size_t)b * 256 + n) * 128 + d];
        ms += v;
        as = fmaf(scores[b * 256 + n], v, as);
    }
    meanp[b * 128 + d] = ms * (1.f / 256.f);
    attnp[b * 128 + d] = as / wsum[b];
}

// ---------------- aggregator
__global__ __launch_bounds__(256) void agg_kernel(
    const float* __restrict__ meanp, const float* __restrict__ attnp,
    const float* __restrict__ gw, const float* __restrict__ gb,
    float* __restrict__ g)
{
    int b = blockIdx.x, j = threadIdx.x;
    __shared__ float cat[256];
    cat[j] = (j < 128) ? meanp[b * 128 + j] : attnp[b * 128 + j - 128];
    __syncthreads();
    float acc = gb[j];
    for (int k = 0; k < 256; k++) acc = fmaf(cat[k], gw[k * 256 + j], acc);
    g[b * 256 + j] = acc > 0.f ? acc : 0.f;
}

// ---------------------------------------------------------------------------
extern "C" void kernel_launch(void* const* d_in, const int* in_sizes, int n_in,
                              void* d_out, int out_size, void* d_ws, size_t ws_size,
                              hipStream_t stream)
{
    (void)in_sizes; (void)n_in; (void)out_size;

    const float* images = (const float*)d_in[0];
    const float* patches = (const float*)d_in[1];
    const float* cw1 = (const float*)d_in[2];
    const float* cb1 = (const float*)d_in[3];
    const float* cw2 = (const float*)d_in[4];
    const float* cb2 = (const float*)d_in[5];
    const float* aw1 = (const float*)d_in[6];
    const float* ab1 = (const float*)d_in[7];
    const float* aw2 = (const float*)d_in[8];
    const float* ab2 = (const float*)d_in[9];
    const float* thr = (const float*)d_in[10];
    const float* bw1 = (const float*)d_in[11];
    const float* bb1 = (const float*)d_in[12];
    const float* bw2 = (const float*)d_in[13];
    const float* bb2 = (const float*)d_in[14];
    const float* bw3 = (const float*)d_in[15];
    const float* bb3 = (const float*)d_in[16];
    const float* bw4 = (const float*)d_in[17];
    const float* bb4 = (const float*)d_in[18];
    const float* sw1 = (const float*)d_in[19];
    const float* sb1 = (const float*)d_in[20];
    const float* sw2 = (const float*)d_in[21];
    const float* sb2 = (const float*)d_in[22];
    const float* gw  = (const float*)d_in[23];
    const float* gb  = (const float*)d_in[24];
    const float* dw1 = (const float*)d_in[25];
    const float* db1 = (const float*)d_in[26];
    const float* cls_w = (const float*)d_in[27];
    const float* cls_b = (const float*)d_in[28];
    const float* reg_w = (const float*)d_in[29];
    const float* reg_b = (const float*)d_in[30];
    float* out = (float*)d_out;
    float* o80 = out;
    float* o4  = out + 655360;

    // ---- workspace carve-up (bytes, 256-aligned)
    unsigned char* base = (unsigned char*)d_ws;
    size_t off = 0;
    auto alloc = [&](size_t bytes) -> unsigned char* {
        unsigned char* r = base + off;
        off += (bytes + 255) & ~(size_t)255;
        return r;
    };

    // fixed-size buffers first
    float*  scores = (float*)alloc(8192 * 4);
    float*  maskf  = (float*)alloc(8192 * 4);
    float*  wsumb  = (float*)alloc(32 * 4);
    float*  combf  = (float*)alloc((size_t)8192 * 128 * 4);
    float*  meanp  = (float*)alloc(4096 * 4);
    float*  attnp  = (float*)alloc(4096 * 4);
    float*  gbuf   = (float*)alloc(8192 * 4);
    float*  wtc2   = (float*)alloc((size_t)64 * 9 * 64 * 4);   // conv2 transposed weights

    typedef unsigned short ush;
    ush* wp_bw1 = (ush*)alloc((size_t)8 * 96 * 4096 * 2);
    ush* wp_bw2 = (ush*)alloc((size_t)8 * 16 * 4096 * 2);
    ush* wp_bw3 = (ush*)alloc((size_t)8 * 16 * 4096 * 2);
    ush* wp_bw4 = (ush*)alloc((size_t)2 * 16 * 4096 * 2);
    ush* wp_sw1 = (ush*)alloc((size_t)1 * 96 * 4096 * 2);
    ush* wp_sw2 = (ush*)alloc((size_t)2 * 2 * 4096 * 2);
    ush* wp_dw1 = (ush*)alloc((size_t)4 * 12 * 4096 * 2);
    ush* wp_det = (ush*)alloc((size_t)2 * 8 * 4096 * 2);

    ush* hb1h = (ush*)alloc((size_t)8192 * 512 * 2);
    ush* hb1l = (ush*)alloc((size_t)8192 * 512 * 2);
    ush* hb2h = (ush*)alloc((size_t)8192 * 512 * 2);
    ush* hb2l = (ush*)alloc((size_t)8192 * 512 * 2);
    ush* hb3h = (ush*)alloc((size_t)8192 * 512 * 2);
    ush* hb3l = (ush*)alloc((size_t)8192 * 512 * 2);
    ush* hsh  = (ush*)alloc((size_t)8192 * 64 * 2);
    ush* hsl  = (ush*)alloc((size_t)8192 * 64 * 2);
    ush* combh = (ush*)alloc((size_t)8192 * 128 * 2);
    ush* combl = (ush*)alloc((size_t)8192 * 128 * 2);
    ush* hdh  = (ush*)alloc((size_t)8192 * 256 * 2);
    ush* hdl  = (ush*)alloc((size_t)8192 * 256 * 2);

    // slice-sized buffers: x1 + tokd
    size_t remain = (ws_size > off) ? (ws_size - off) : 0;
    int SL = 8;
    while (SL > 1) {
        size_t need = (size_t)SL * 64 * 256 * 256 * 4 + (size_t)SL * 64 * 128 * 16 * 8 + 1024;
        if (need <= remain) break;
        SL >>= 1;
    }
    float*  x1   = (float*)alloc((size_t)SL * 64 * 256 * 256 * 4);
    double* tokd = (double*)alloc((size_t)SL * 64 * 128 * 16 * 8);

    // patches split buffers (fragment-tiled): alias the dead x1 region when big
    // enough (SL=8: 134MB >= 100.7MB), else dedicated alloc, else fall back.
    const size_t ps_bytes = (size_t)8192 * 3072 * 2;   // 50.33 MB per plane
    ush* psh = nullptr;
    ush* psl = nullptr;
    int have_split = 0;
    if ((size_t)SL * 64 * 256 * 256 * 4 >= 2 * ps_bytes) {
        psh = (ush*)x1;
        psl = (ush*)((unsigned char*)x1 + ps_bytes);
        have_split = 1;
    } else {
        size_t rem2 = (ws_size > off) ? (ws_size - off) : 0;
        if (rem2 >= 2 * ps_bytes + 1024) {
            psh = (ush*)alloc(ps_bytes);
            psl = (ush*)alloc(ps_bytes);
            have_split = 1;
        }
    }

    // ---- weight preps
    {
        wprep_conv2<<<(64 * 9 * 64 + 255) / 256, 256, 0, stream>>>(cw2, wtc2);
        int t1 = 8 * 96 * 4 * 64;  wprep<<<(t1 + 255) / 256, 256, 0, stream>>>(bw1, wp_bw1, 3072, 512, 512);
        int t2 = 8 * 16 * 4 * 64;  wprep<<<(t2 + 255) / 256, 256, 0, stream>>>(bw2, wp_bw2, 512, 512, 512);
                                   wprep<<<(t2 + 255) / 256, 256, 0, stream>>>(bw3, wp_bw3, 512, 512, 512);
        int t4 = 2 * 16 * 4 * 64;  wprep<<<(t4 + 255) / 256, 256, 0, stream>>>(bw4, wp_bw4, 512, 128, 128);
        int t5 = 1 * 96 * 4 * 64;  wprep<<<(t5 + 255) / 256, 256, 0, stream>>>(sw1, wp_sw1, 3072, 64, 64);
        int t6 = 2 * 2 * 4 * 64;   wprep<<<(t6 + 255) / 256, 256, 0, stream>>>(sw2, wp_sw2, 64, 128, 128);
        int t7 = 4 * 12 * 4 * 64;  wprep<<<(t7 + 255) / 256, 256, 0, stream>>>(dw1, wp_dw1, 384, 256, 256);
        int t8 = 2 * 8 * 4 * 64;   wprep_det<<<(t8 + 255) / 256, 256, 0, stream>>>(cls_w, reg_w, wp_det);
    }

    // ---- backbone + attention scores, batch-sliced
    for (int s = 0; s < B_ALL / SL; s++) {
        conv1_kernel<<<dim3(256, SL), 256, 0, stream>>>(images, cw1, cb1, x1, s * SL);
        conv2_kernel<<<dim3(128, SL), 256, 0, stream>>>(x1, wtc2, cb2, tokd);
        attn_kernel<<<dim3(256, SL), 64, 0, stream>>>(tokd, aw1, ab1, aw2, ab2,
                                                      thr, scores, maskf, s * SL);
    }
    wsum_kernel<<<32, 256, 0, stream>>>(scores, wsumb);

    // ---- experts (split-bf16 MFMA)
    if (have_split) {
        asplit_kernel<<<(8192 * 3072) / (8 * 256), 256, 0, stream>>>(patches, psh, psl);
        mgemm<1, 1, 0, 2, 0><<<dim3(8, 64), 256, 0, stream>>>(
            nullptr, psh, psl, wp_bw1, bb1, nullptr, hb1h, hb1l, nullptr,
            3072, 512, 96, nullptr, nullptr, nullptr, nullptr);
        mgemm<1, 1, 0, 2, 0><<<dim3(1, 64), 256, 0, stream>>>(
            nullptr, psh, psl, wp_sw1, sb1, nullptr, hsh, hsl, nullptr,
            3072, 64, 96, nullptr, nullptr, nullptr, nullptr);
    } else {
        mgemm<0, 1, 0, 2, 0><<<dim3(8, 64), 256, 0, stream>>>(
            patches, nullptr, nullptr, wp_bw1, bb1, nullptr, hb1h, hb1l, nullptr,
            3072, 512, 96, nullptr, nullptr, nullptr, nullptr);
        mgemm<0, 1, 0, 2, 0><<<dim3(1, 64), 256, 0, stream>>>(
            patches, nullptr, nullptr, wp_sw1, sb1, nullptr, hsh, hsl, nullptr,
            3072, 64, 96, nullptr, nullptr, nullptr, nullptr);
    }
    mgemm<1, 1, 0, 2, 0><<<dim3(8, 64), 256, 0, stream>>>(
        nullptr, hb1h, hb1l, wp_bw2, bb2, nullptr, hb2h, hb2l, nullptr,
        512, 512, 16, nullptr, nullptr, nullptr, nullptr);
    mgemm<1, 1, 0, 2, 0><<<dim3(8, 64), 256, 0, stream>>>(
        nullptr, hb2h, hb2l, wp_bw3, bb3, nullptr, hb3h, hb3l, nullptr,
        512, 512, 16, nullptr, nullptr, nullptr, nullptr);
    mgemm<1, 0, 1, 3, 0><<<dim3(2, 64), 256, 0, stream>>>(
        nullptr, hb3h, hb3l, wp_bw4, bb4, combf, combh, combl, maskf,
        512, 128, 16, nullptr, nullptr, nullptr, nullptr);
    mgemm<1, 0, 2, 3, 0><<<dim3(2, 64), 256, 0, stream>>>(
        nullptr, hsh, hsl, wp_sw2, sb2, combf, combh, combl, maskf,
        64, 128, 2, nullptr, nullptr, nullptr, nullptr);

    // ---- aggregate + detection
    pool2_kernel<<<32, 128, 0, stream>>>(combf, scores, wsumb, meanp, attnp);
    agg_kernel<<<32, 256, 0, stream>>>(meanp, attnp, gw, gb, gbuf);
    mgemm<2, 1, 0, 2, 0><<<dim3(4, 64), 256, 0, stream>>>(
        gbuf, combh, combl, wp_dw1, db1, nullptr, hdh, hdl, nullptr,
        384, 256, 12, nullptr, nullptr, nullptr, nullptr);
    mgemm<1, 0, 0, 0, 1><<<dim3(2, 64), 256, 0, stream>>>(
        nullptr, hdh, hdl, wp_det, nullptr, nullptr, nullptr, nullptr, nullptr,
        256, 128, 8, o80, o4, cls_b, reg_b);
}